// Round 5
// baseline (412.518 us; speedup 1.0000x reference)
//

#include <hip/hip_runtime.h>
#include <hip/hip_bf16.h>

// ROUND 25 (round 24: 346.8 us, absmax 0.0; gemm LDS-staging worked, sink_persist
// back on top at 101 us. Model: ~42 substep barriers x ~2.8us serial release
// chain (group RMW -> global RMW -> flag stores -> poller read) = ~80us):
//  - gridbar rebuilt: drop global counter + release flags. Arrival = 1 RMW on
//    own group counter (32 groups x 32 blocks, monotonic, 64B padded).
//    Release = wave-parallel poll: lanes 0-31 of wave 0 each load one group
//    counter, __all(v >= 32*phase). Chain 4 LLC hops -> 2 (~1.4us/barrier).
//  - everything else byte-identical to round 24.

#define NN 4096
#define LDA 4104          /* fp16 row stride for S (4097 padded to x8) */
#define DD 512
#define NCNUM 409         /* int(0.1*4096) */
#define REGc 0.03f
#define INVREG (1.0f/0.03f)
#define GAM 0.8f
#define THRESHc 1e-4f
#define LOGN 8.3177661667193433f   /* ln(4096) */
#define LOGM 8.3180102775477533f   /* ln(4097) */
#define NEGINF (-__builtin_inff())

typedef unsigned short u16;
typedef unsigned int u32;
typedef _Float16 f16;

struct alignas(16) Q  { u32 x, y, z, w; };
union H8 { Q q; f16 h[8]; };

typedef __attribute__((ext_vector_type(8))) short frag_ab;   /* 8 bf16 */
typedef __attribute__((ext_vector_type(4))) float frag_cd;   /* 4 f32  */

__device__ __forceinline__ float bf2f(u32 u) { return __uint_as_float(u << 16); }
__device__ __forceinline__ float bflo(u32 w) { return __uint_as_float(w << 16); }
__device__ __forceinline__ float bfhi(u32 w) { return __uint_as_float(w & 0xFFFF0000u); }
__device__ __forceinline__ u16 f2bf_rne(float f) {
  u32 b = __float_as_uint(f);
  b += 0x7FFFu + ((b >> 16) & 1u);
  return (u16)(b >> 16);
}
__device__ __forceinline__ u16 f2h_hw(float f) {
  union { f16 h; u16 u; } X; X.h = (f16)f; return X.u;
}
__device__ __forceinline__ float h2f_hw(u16 v) {
  union { u16 u; f16 h; } X; X.u = v; return (float)X.h;
}
__device__ __forceinline__ float exp2_fast(float x) {
#if __has_builtin(__builtin_amdgcn_exp2f)
  return __builtin_amdgcn_exp2f(x);
#else
  float r; asm("v_exp_f32 %0, %1" : "=v"(r) : "v"(x)); return r;
#endif
}
/* LLC-point (agent-scope, relaxed) load/store: no L2 invalidate/writeback */
__device__ __forceinline__ float ldu(const float* p) {
  return __hip_atomic_load(p, __ATOMIC_RELAXED, __HIP_MEMORY_SCOPE_AGENT);
}
__device__ __forceinline__ void stu(float* p, float v) {
  __hip_atomic_store(p, v, __ATOMIC_RELAXED, __HIP_MEMORY_SCOPE_AGENT);
}
/* async global->LDS, 16B per lane; lds base must be wave-uniform */
__device__ __forceinline__ void gload_lds16(const u16* g, u16* l) {
  __builtin_amdgcn_global_load_lds(
      (const __attribute__((address_space(1))) u32*)g,
      (__attribute__((address_space(3))) u32*)l, 16, 0, 0);
}
__device__ __forceinline__ void unpack8(Q q, float* x) {
  H8 u; u.q = q;
  #pragma unroll
  for (int c = 0; c < 8; ++c) x[c] = (float)u.h[c];
}
__device__ __forceinline__ void lse_merge(float& m, float& s, float om, float os) {
  float nm = fmaxf(m, om);
  if (nm == NEGINF) return;
  float acc = 0.f;
  if (s  > 0.f) acc += s  * __expf(m  - nm);
  if (os > 0.f) acc += os * __expf(om - nm);
  m = nm; s = acc;
}
__device__ __forceinline__ float blockReduce256(float v) {
  __shared__ float sh[4];
  #pragma unroll
  for (int off = 32; off >= 1; off >>= 1) v += __shfl_xor(v, off);
  int w = threadIdx.x >> 6;
  if ((threadIdx.x & 63) == 0) sh[w] = v;
  __syncthreads();
  float r = 0.f;
  if (threadIdx.x == 0) r = sh[0] + sh[1] + sh[2] + sh[3];
  __syncthreads();
  return r;
}

__global__ void ContrastiveLoss_83391085019222_kernel(float* out) {
  if (threadIdx.x == 0) { out[0] = 0.5f; out[1] = 0.5f; }
}
__global__ void diag_kernel(float* out, float a, float b) {
  if (threadIdx.x == 0) { out[0] = a; out[1] = b; }
}

/* ---- dtype autodetect: inputs are unit-normalized rows ---- */
__global__ void detect_kernel(const u16* img, float* misc) {
  const int lane = threadIdx.x;  /* 64 */
  float nb = 0.f, nf = 0.f;
  const float* fimg = (const float*)img;
  for (int c = lane * 8; c < lane * 8 + 8; ++c) {
    float xb = bf2f((u32)img[c]);
    nb += xb * xb;
    float xf = fimg[c];
    if (fabsf(xf) < 1e10f) nf += xf * xf; else nf += 1e10f;
  }
  #pragma unroll
  for (int off = 32; off >= 1; off >>= 1) { nb += __shfl_xor(nb, off); nf += __shfl_xor(nf, off); }
  if (lane == 0) {
    float db = fabsf(nb - 1.f);
    float df = fabsf(nf - 1.f);
    if (!(db == db)) db = 1e30f;
    if (!(df == df)) df = 1e30f;
    ((int*)misc)[10] = (df < db) ? 1 : 0;   /* 1 = float32 inputs */
  }
}

/* ---- convert img/txt to bf16 planes ---- */
__global__ void cvt_kernel(const u16* img, const u16* txt,
                           u16* Abf, u16* Bbf, const float* misc) {
  const int isF = ((const int*)misc)[10];
  const int t = blockIdx.x * 256 + threadIdx.x;
  const int base = t * 4;
  if (isF) {
    const float* fi = (const float*)img;
    const float* ft = (const float*)txt;
    ushort4 oa, ob;
    oa.x = f2bf_rne(fi[base+0]); oa.y = f2bf_rne(fi[base+1]);
    oa.z = f2bf_rne(fi[base+2]); oa.w = f2bf_rne(fi[base+3]);
    ob.x = f2bf_rne(ft[base+0]); ob.y = f2bf_rne(ft[base+1]);
    ob.z = f2bf_rne(ft[base+2]); ob.w = f2bf_rne(ft[base+3]);
    *(ushort4*)(Abf + base) = oa;
    *(ushort4*)(Bbf + base) = ob;
  } else {
    *(ushort4*)(Abf + base) = *(const ushort4*)(img + base);
    *(ushort4*)(Bbf + base) = *(const ushort4*)(txt + base);
  }
}

/* init: zero vecs(16400) + errs(256) + rsA0(4096) + csA0(4104) + bar(1024), scale */
__global__ void init_kernel(const u16* ls, float* vecs, float* errs,
                            float* rsA0, float* csA0, int* bar, float* misc) {
  int t = blockIdx.x * 256 + threadIdx.x;
  if (t < 16400) vecs[t] = 0.f;
  if (t < 256)  errs[t] = 0.f;
  if (t < 4096) rsA0[t] = 0.f;
  if (t < 4104) csA0[t] = 0.f;
  if (t < 1024) bar[t] = 0;
  if (t == 0) {
    const int isF = ((const int*)misc)[10];
    float lsv = isF ? ((const float*)ls)[0] : bf2f((u32)ls[0]);
    misc[0] = __expf(lsv);               /* scale = exp(logit_scale) */
  }
}

/* ------- MFMA GEMM (m97 structure): S = Abf x Bbf^T -> fp16 + min ------- */
__global__ __launch_bounds__(256) void gemm_mfma(const u16* Abf, const u16* Bbf,
                                                 u16* S, float* gmin) {
  __shared__ float red[256];
  __shared__ u16 ldsA[128 * 64];
  __shared__ u16 ldsB[128 * 64];
  const int tid = threadIdx.x;
  const int wave = tid >> 6, lane = tid & 63;
  const int wr = wave >> 1, wc = wave & 1;
  const int rb = (int)blockIdx.y * 128;
  const int cb = (int)blockIdx.x * 128;
  const int l15 = lane & 15, q = lane >> 4;
  const int srow = lane >> 3;          /* 0..7 row within 8-row issue group */
  const int scol = (lane & 7) * 8;     /* col element (x8, 16B) */

  frag_cd acc[4][4];
  #pragma unroll
  for (int i = 0; i < 4; ++i)
    #pragma unroll
    for (int j = 0; j < 4; ++j) acc[i][j] = (frag_cd){0.f, 0.f, 0.f, 0.f};

  for (int kt = 0; kt < DD; kt += 64) {
    __syncthreads();                   /* previous compute done before overwrite */
    #pragma unroll
    for (int i = 0; i < 4; ++i) {
      const int R = (wave * 4 + i) * 8;   /* wave-uniform 8-row group */
      gload_lds16(Abf + (size_t)(rb + R + srow) * DD + kt + scol, &ldsA[R * 64]);
      gload_lds16(Bbf + (size_t)(cb + R + srow) * DD + kt + scol, &ldsB[R * 64]);
    }
    __syncthreads();                   /* vmcnt(0) drain: tiles resident */
    #pragma unroll
    for (int s = 0; s < 2; ++s) {
      frag_ab af[4], bfr[4];
      #pragma unroll
      for (int t = 0; t < 4; ++t) {
        af[t]  = *(const frag_ab*)&ldsA[(wr * 64 + t * 16 + l15) * 64 + s * 32 + q * 8];
        bfr[t] = *(const frag_ab*)&ldsB[(wc * 64 + t * 16 + l15) * 64 + s * 32 + q * 8];
      }
      #pragma unroll
      for (int i = 0; i < 4; ++i)
        #pragma unroll
        for (int j = 0; j < 4; ++j)
          acc[i][j] = __builtin_amdgcn_mfma_f32_16x16x32_bf16(af[i], bfr[j], acc[i][j], 0, 0, 0);
    }
  }

  float lmin = 1e30f;
  #pragma unroll
  for (int i = 0; i < 4; ++i) {
    #pragma unroll
    for (int j = 0; j < 4; ++j) {
      #pragma unroll
      for (int r = 0; r < 4; ++r) {
        const int row = rb + wr * 64 + i * 16 + q * 4 + r;
        const int col = cb + wc * 64 + j * 16 + l15;
        u16 h = f2h_hw(acc[i][j][r]);
        lmin = fminf(lmin, h2f_hw(h));
        S[(size_t)row * LDA + col] = h;
      }
    }
  }
  red[tid] = lmin;
  __syncthreads();
  for (int sN = 128; sN >= 1; sN >>= 1) {
    if (tid < sN) red[tid] = fminf(red[tid], red[tid + sN]);
    __syncthreads();
  }
  if (tid == 0) gmin[blockIdx.y * 32 + blockIdx.x] = red[0];
}

/* ------- sims_no -> S col NN + loss_op partial ------- */
__global__ void colvec_kernel(const u16* img, const u16* txt, const u16* tno,
                              u16* S, float* colvals, float* opP, const float* misc) {
  __shared__ float shOp[4];
  const int isF = ((const int*)misc)[10];
  const int wv = threadIdx.x >> 6;
  const int row = (int)(blockIdx.x << 2) + wv;
  const int lane = threadIdx.x & 63;
  const size_t base = (size_t)row * DD + lane * 8;
  float xi[8], xt[8], xn[8];
  if (isF) {
    const float* fi = (const float*)img;
    const float* ft = (const float*)txt;
    const float* fn = (const float*)tno;
    #pragma unroll
    for (int c = 0; c < 8; ++c) { xi[c] = fi[base+c]; xt[c] = ft[base+c]; xn[c] = fn[base+c]; }
  } else {
    Q qi = *(const Q*)(img + base);
    Q qt = *(const Q*)(txt + base);
    Q qn = *(const Q*)(tno + base);
    xi[0]=bflo(qi.x); xi[1]=bfhi(qi.x); xi[2]=bflo(qi.y); xi[3]=bfhi(qi.y);
    xi[4]=bflo(qi.z); xi[5]=bfhi(qi.z); xi[6]=bflo(qi.w); xi[7]=bfhi(qi.w);
    xt[0]=bflo(qt.x); xt[1]=bfhi(qt.x); xt[2]=bflo(qt.y); xt[3]=bfhi(qt.y);
    xt[4]=bflo(qt.z); xt[5]=bfhi(qt.z); xt[6]=bflo(qt.w); xt[7]=bfhi(qt.w);
    xn[0]=bflo(qn.x); xn[1]=bfhi(qn.x); xn[2]=bflo(qn.y); xn[3]=bfhi(qn.y);
    xn[4]=bflo(qn.z); xn[5]=bfhi(qn.z); xn[6]=bflo(qn.w); xn[7]=bfhi(qn.w);
  }
  float sn = 0.f, cs = 0.f;
  #pragma unroll
  for (int c = 0; c < 8; ++c) { sn += xi[c]*xn[c]; cs += xt[c]*xn[c]; }
  #pragma unroll
  for (int off = 32; off >= 1; off >>= 1) { sn += __shfl_xor(sn, off); cs += __shfl_xor(cs, off); }
  if (lane == 0) {
    colvals[row] = sn;
    S[(size_t)row * LDA + NN] = f2h_hw(sn);
    shOp[wv] = fmaxf(cs + 0.2f, 0.f) + fmaxf(-0.7f - cs, 0.f);
  }
  __syncthreads();
  if (threadIdx.x == 0) opP[blockIdx.x] = shOp[0] + shOp[1] + shOp[2] + shOp[3];
}

__global__ void reduce_kernel(const float* gmin, const float* colvals,
                              const float* opP, float* misc) {
  __shared__ float smin[256];
  __shared__ float ssum[256];
  float mn = 1e30f, sm = 0.f;
  for (int i = threadIdx.x; i < 1024; i += 256) mn = fminf(mn, gmin[i]);
  for (int i = threadIdx.x; i < 4096; i += 256) mn = fminf(mn, h2f_hw(f2h_hw(colvals[i])));
  for (int i = threadIdx.x; i < 1024; i += 256) sm += opP[i];
  smin[threadIdx.x] = mn; ssum[threadIdx.x] = sm;
  __syncthreads();
  for (int sN = 128; sN >= 1; sN >>= 1) {
    if (threadIdx.x < sN) {
      smin[threadIdx.x] = fminf(smin[threadIdx.x], smin[threadIdx.x + sN]);
      ssum[threadIdx.x] += ssum[threadIdx.x + sN];
    }
    __syncthreads();
  }
  if (threadIdx.x == 0) {
    float maxC = 1.0f - smin[0];         /* max(1-S) = 1 - min(S) */
    float a = 1.0f / (maxC * REGc);
    misc[1] = a;
    misc[4] = ssum[0];
    misc[5] = __expf(-a);                /* ea */
    misc[6] = a * 1.4426950408889634f;   /* b = a*log2(e) for exp2 fast path */
  }
}

__global__ void preds_kernel(const u16* S, const float* misc, float* preds) {
  const int row = (int)(blockIdx.x << 2) + (int)(threadIdx.x >> 6);
  const int lane = threadIdx.x & 63;
  const float scale = misc[0];
  const u16* Sr = S + (size_t)row * LDA;
  float m = NEGINF, s = 0.f;
  for (int it = 0; it < 8; ++it) {
    const int j0 = (it << 9) + (lane << 3);
    float x[8];
    unpack8(*(const Q*)(Sr + j0), x);
    float lm = NEGINF;
    #pragma unroll
    for (int c = 0; c < 8; ++c) { x[c] *= scale; lm = fmaxf(lm, x[c]); }
    float lsum = 0.f;
    #pragma unroll
    for (int c = 0; c < 8; ++c) lsum += __expf(x[c] - lm);
    lse_merge(m, s, lm, lsum);
  }
  #pragma unroll
  for (int off = 32; off >= 1; off >>= 1) {
    float om = __shfl_xor(m, off), os = __shfl_xor(s, off);
    lse_merge(m, s, om, os);
  }
  if (lane == 0) {
    float sii = h2f_hw(Sr[row]);
    preds[row] = __expf(scale * sii - m) / s;
  }
}

/* ------- nc rank: one block per row ------- */
__global__ void rank_kernel(const float* preds, int* is_nc) {
  const int i = blockIdx.x;
  const float pv = preds[i];
  float cnt = 0.f;
  for (int k2 = threadIdx.x; k2 < NN; k2 += 256) {
    float pk = preds[k2];
    cnt += (pk < pv || (pk == pv && k2 < i)) ? 1.f : 0.f;
  }
  cnt = blockReduce256(cnt);
  if (threadIdx.x == 0) is_nc[i] = (cnt < (float)NCNUM) ? 1 : 0;
}

__device__ __forceinline__ bool unmasked(int j, int r, bool ncr) {
  return (j == NN) ? ncr : !((j == r) && ncr);
}

/* ------- fence-free monotonic barrier, wave-parallel release detect -------
   Arrival: 1 relaxed-agent RMW on own group counter (32 groups x 32 blocks,
   64B padded). Release: lanes 0-31 of wave 0 each poll one group counter;
   __all(v >= 32*phase). 2 LLC hops on the critical chain (vs 4 with the
   global-counter + flag design). Monotonic counters, no resets. */
__device__ __forceinline__ void gridbar(int* bar, int bid, int phase, bool& dead) {
  __syncthreads();
  if (threadIdx.x < 64 && !dead) {
    if (threadIdx.x == 0)
      __hip_atomic_fetch_add(&bar[(bid & 31) << 4], 1, __ATOMIC_RELAXED,
                             __HIP_MEMORY_SCOPE_AGENT);
    const int lane = threadIdx.x;
    const int target = 32 * phase;
    int spins = 0;
    for (;;) {
      int v = target;
      if (lane < 32)
        v = __hip_atomic_load(&bar[lane << 4], __ATOMIC_RELAXED,
                              __HIP_MEMORY_SCOPE_AGENT);
      if (__all(v >= target)) break;
      __builtin_amdgcn_s_sleep(4);
      if (++spins > (1 << 20)) { dead = true; break; }   /* ~0.1s sticky cap */
    }
  }
  __syncthreads();
}

/* ------- one sinkhorn sub-step with cached E (gates passed in) ---- */
template<int RB, int FIN>
__device__ __forceinline__ void substep(
    float (&Ec)[8][8], int k,
    int c1, int c2, int c1p, int c2p,
    const float* prevRow, const float* prevCol,
    float* outRow, float* outCol,
    float* z1, float* z2, int nz1, int nz2,
    float* errs1, float* errs2,
    float* uvec, float* utvec, float* vvec, float* vtvec,
    float* shW1, float* shW2, float (*shAcc)[128], float* sh4096,
    float* se,
    float ea, int rt, int ct, int bid, int tid, int tc, int tr,
    int j0c, int r0, int cbase, bool isLast) {

  const int gRow = RB ? c2 : c1;
  const int gCol = RB ? c1 : c2;

  if (!FIN) {
    const int z = bid * 256 + tid;          /* 8200 < 262144: one shot */
    if (z < nz1) stu(&z1[z], 0.f);
    else if (z - nz1 < nz2) stu(&z2[z - nz1], 0.f);
  }

  /* speculative LLC loads of prev sums (overlap with zeroing) */
  float pr = 0.f, prN = 0.f;
  if (tid < 128) {
    pr = ldu(&prevRow[r0 + tid]);
  } else {
    pr = ldu(&prevCol[cbase + (tid - 128)]);
    if (isLast && tid == 128) prN = ldu(&prevCol[NN]);
  }

  float errd = 0.f;
  if (tid < 128) {
    const int i = r0 + tid;
    float w = 0.f;
    if (!RB) {
      if (!FIN && !gCol) w = (k == 0) ? ea : ea / (4096.0f * pr);
      if (ct == 0 && k >= 1 && !c2p) vtvec[i] = REGc * (-LOGN - __logf(pr));
    } else {
      if (!gCol) {
        w = ea / (4096.0f * pr);
        if (ct == 0) {
          float un = REGc * (-LOGN - __logf(pr));
          errd = fabsf(un - uvec[i]);
          uvec[i] = un;
        }
      }
    }
    shW2[tid] = w;
  } else {
    const int j = cbase + (tid - 128);
    float w = 0.f;
    if (!RB) {
      if (!FIN && !gRow) w = (k == 0) ? ea : ea / (4097.0f * pr);
      if (rt == 0 && k >= 1 && !c1p) vvec[j] = REGc * (-LOGM - __logf(pr));
    } else {
      if (!gRow) {
        w = ea / (4097.0f * pr);
        if (rt == 0) {
          float un = REGc * (-LOGM - __logf(pr));
          errd = fabsf(un - utvec[j]);
          utvec[j] = un;
        }
      }
    }
    shW1[tid - 128] = w;
    if (isLast && tid == 128) {        /* col 4096 sidecar weight */
      float w2 = 0.f;
      if (!RB) {
        if (!FIN && !gRow) w2 = (k == 0) ? ea : ea / (4097.0f * prN);
        if (rt == 0 && k >= 1 && !c1p) vvec[NN] = REGc * (-LOGM - __logf(prN));
      } else {
        if (!gRow) {
          w2 = ea / (4097.0f * prN);
          if (rt == 0) {
            float un = REGc * (-LOGM - __logf(prN));
            errd += fabsf(un - utvec[NN]);
            utvec[NN] = un;
          }
        }
      }
      shW1[128] = w2;
    }
  }
  __syncthreads();

  if (!FIN && !(gRow && gCol)) {
    float W1l[8];
    #pragma unroll
    for (int c = 0; c < 8; ++c) W1l[c] = shW1[j0c + c];
    float cs[8];
    #pragma unroll
    for (int c = 0; c < 8; ++c) cs[c] = 0.f;
    const float w4096 = isLast ? shW1[128] : 0.f;
    #pragma unroll
    for (int st = 0; st < 8; ++st) {
      const int rr = (st << 4) + tr;
      if (!gCol) {
        const float Wr = shW2[rr];
        #pragma unroll
        for (int c = 0; c < 8; ++c) cs[c] = fmaf(Ec[st][c], Wr, cs[c]);
      }
      if (!gRow) {
        float rs = 0.f;
        #pragma unroll
        for (int c = 0; c < 8; ++c) rs = fmaf(Ec[st][c], W1l[c], rs);
        #pragma unroll
        for (int off = 8; off >= 1; off >>= 1) rs += __shfl_xor(rs, off);
        if (tc == 0) {
          if (isLast) rs += sh4096[rr] * w4096;
          atomicAdd(&outRow[r0 + rr], rs);
        }
      }
    }
    if (!gCol) {
      #pragma unroll
      for (int c = 0; c < 8; ++c) shAcc[tr][j0c + c] = cs[c];
      __syncthreads();
      if (tid < 128) {
        float s2 = 0.f;
        #pragma unroll
        for (int g = 0; g < 16; ++g) s2 += shAcc[g][tid];
        atomicAdd(&outCol[cbase + tid], s2);
      }
      if (isLast && tid >= 128 && tid < 192) {   /* colsum for j=4096 */
        const int l = tid - 128;
        float s3 = sh4096[l] * shW2[l] + sh4096[l + 64] * shW2[l + 64];
        #pragma unroll
        for (int off = 32; off >= 1; off >>= 1) s3 += __shfl_xor(s3, off);
        if (l == 0) atomicAdd(&outCol[NN], s3);
      }
    }
  }

  if (RB) {
    float e2 = errd;
    #pragma unroll
    for (int off = 32; off >= 1; off >>= 1) e2 += __shfl_xor(e2, off);
    if ((tid & 63) == 0) se[tid >> 6] = e2;
    __syncthreads();
    if (tid == 0) {
      if (ct == 0) atomicAdd(&errs1[k], se[0] + se[1]);
      if (rt == 0) atomicAdd(&errs2[k], se[2] + se[3]);
    }
  }
}

/* ------- persistent sinkhorn: all iterations, E cached, early break ------- */
__global__ __launch_bounds__(256, 4) void sink_persist(
    const u16* S, const float* misc, float* errs1, float* errs2,
    float* uvec, float* utvec, float* vvec, float* vtvec,
    float* rsA0, float* rsA1, float* csA0, float* csA1,
    float* rsB0, float* rsB1, float* csB0, float* csB1,
    const int* is_nc, int* bar) {
  __shared__ float shW1[129];
  __shared__ float shW2[128];
  __shared__ float shAcc[16][128];
  __shared__ float sh4096[128];
  __shared__ int   shG[4];
  __shared__ float se[4];

  const int tid = threadIdx.x;
  const int rt = blockIdx.x, ct = blockIdx.y;
  const int bid = ct * 32 + rt;
  const int cbase = ct << 7, r0 = rt << 7;
  const float a = misc[1], ea = misc[5], b = misc[6];
  const int tc = tid & 15, tr = tid >> 4;
  const int j0c = tc << 3;
  const bool isLast = (ct == 31);

  /* ---- build E tile in registers, masks baked in ---- */
  float Ec[8][8];
  if (rt != ct) {
    #pragma unroll
    for (int st = 0; st < 8; ++st) {
      const int rr = (st << 4) + tr;
      H8 hh; hh.q = *(const Q*)(S + (size_t)(r0 + rr) * LDA + cbase + j0c);
      #pragma unroll
      for (int c = 0; c < 8; ++c) Ec[st][c] = exp2_fast((float)hh.h[c] * b);
    }
  } else {
    #pragma unroll
    for (int st = 0; st < 8; ++st) {
      const int rr = (st << 4) + tr;
      const int r = r0 + rr;
      float xv[8];
      unpack8(*(const Q*)(S + (size_t)r * LDA + cbase + j0c), xv);
      const bool ncr = (is_nc[r] != 0);
      #pragma unroll
      for (int c = 0; c < 8; ++c) {
        float e = __expf(xv[c] * a);
        if ((j0c + c == rr) && ncr) e = 0.f;   /* diag mask (cbase==r0) */
        Ec[st][c] = e;
      }
    }
  }
  if (isLast && tid < 128) {
    const int r = r0 + tid;
    float x = h2f_hw(S[(size_t)r * LDA + NN]);
    sh4096[tid] = (is_nc[r] != 0) ? __expf(x * a) : 0.f;
  }
  __syncthreads();

  bool dead = false;
  int phase = 0;
  for (int k = 0; k < 100; ++k) {
    const int p = k & 1;
    const int q2 = 1 - p;
    const int pm = (k > 0) ? q2 : 0;
    /* gates for iteration k (identical for substeps A and B) */
    if (tid < 4) {
      const int kk = k - 1 - (tid >> 1);
      const float* ep = (tid & 1) ? errs2 : errs1;
      shG[tid] = (kk >= 0) && (ldu(&ep[kk]) < THRESHc);
    }
    __syncthreads();
    const int c1 = shG[0], c2 = shG[1], c1p = shG[2], c2p = shG[3];
    if (c1 && c2 && c1p && c2p) break;   /* remaining substeps provably no-op */

    substep<0, 0>(Ec, k, c1, c2, c1p, c2p,
        pm ? rsB1 : rsB0, pm ? csB1 : csB0,
        p ? rsA1 : rsA0, p ? csA1 : csA0,
        p ? csB1 : csB0, p ? rsB1 : rsB0, 4104, 4096,
        errs1, errs2, uvec, utvec, vvec, vtvec,
        shW1, shW2, shAcc, sh4096, se,
        ea, rt, ct, bid, tid, tc, tr, j0c, r0, cbase, isLast);
    gridbar(bar, bid, ++phase, dead);

    substep<1, 0>(Ec, k, c1, c2, c1p, c2p,
        p ? rsA1 : rsA0, p ? csA1 : csA0,
        p ? rsB1 : rsB0, p ? csB1 : csB0,
        q2 ? rsA1 : rsA0, q2 ? csA1 : csA0, 4096, 4104,
        errs1, errs2, uvec, utvec, vvec, vtvec,
        shW1, shW2, shAcc, sh4096, se,
        ea, rt, ct, bid, tid, tc, tr, j0c, r0, cbase, isLast);
    gridbar(bar, bid, ++phase, dead);
  }

  /* final weight-only step (k=100); gates for k=100 (all-true if broken) */
  if (tid < 4) {
    const int kk = 99 - (tid >> 1);
    const float* ep = (tid & 1) ? errs2 : errs1;
    shG[tid] = (ldu(&ep[kk]) < THRESHc);
  }
  __syncthreads();
  substep<0, 1>(Ec, 100, shG[0], shG[1], shG[2], shG[3],
      rsB1, csB1, rsA0, csA0, rsA0, csA0, 0, 0,
      errs1, errs2, uvec, utvec, vvec, vtvec,
      shW1, shW2, shAcc, sh4096, se,
      ea, rt, ct, bid, tid, tc, tr, j0c, r0, cbase, isLast);
}

/* ------- final pass 1 (128x128 tiles, grid (33,32)) ------- */
__global__ __launch_bounds__(256) void final_pass(const u16* S, const float* vvec,
                           const float* vtvec, const float* misc, const int* is_nc,
                           float* rowLm, float* rowLs, float* rowGs,
                           float* colLm, float* colLs, float* colGs) {
  const float a = misc[1], scale = misc[0];
  const int ct = blockIdx.x, rt = blockIdx.y;
  const int tid = threadIdx.x;
  const int tc = tid & 15, tr = tid >> 4;
  const int cbase = ct << 7, r0 = rt << 7;
  const int j0 = cbase + (tc << 3);
  const bool anyv = (j0 <= NN);
  float wc[8]; unsigned jval = 0;
  #pragma unroll
  for (int c = 0; c < 8; ++c) {
    int j = j0 + c;
    wc[c] = 0.f;
    if (j <= NN) { jval |= 1u << c; wc[c] = vvec[j] * INVREG; }
  }
  float cLm[8], cLs[8], cGs[8];
  #pragma unroll
  for (int c = 0; c < 8; ++c) { cLm[c] = NEGINF; cLs[c] = 0.f; cGs[c] = 0.f; }
  for (int st = 0; st < 8; ++st) {
    const int r = r0 + (st << 4) + tr;
    float xv[8], lg[8]; unsigned um = 0;
    #pragma unroll
    for (int c = 0; c < 8; ++c) { xv[c] = 0.f; lg[c] = 0.f; }
    if (anyv) {
      float raw[8];
      unpack8(*(const Q*)(S + (size_t)r * LDA + j0), raw);
      const bool ncr = (is_nc[r] != 0);
      const float vtr = vtvec[r] * INVREG;
      #pragma unroll
      for (int c = 0; c < 8; ++c) {
        if (!(jval >> c & 1u)) continue;
        xv[c] = raw[c] * a;
        lg[c] = scale * raw[c];
        cGs[c] += __expf(lg[c]);
        if (unmasked(j0 + c, r, ncr)) {
          um |= 1u << c;
          float e2 = xv[c] + vtr;
          float nm = fmaxf(cLm[c], e2);
          cLs[c] = cLs[c] * __expf(cLm[c] - nm) + __expf(e2 - nm);
          cLm[c] = nm;
        }
      }
    }
    float rsG = 0.f;
    if (anyv) {
      #pragma unroll
      for (int c = 0; c < 8; ++c) if (jval >> c & 1u) rsG += __expf(lg[c]);
    }
    #pragma unroll
    for (int off = 8; off >= 1; off >>= 1) rsG += __shfl_xor(rsG, off);
    float rmL = NEGINF;
    if (anyv) {
      #pragma unroll
      for (int c = 0; c < 8; ++c) if (um >> c & 1u) rmL = fmaxf(rmL, xv[c] + wc[c]);
    }
    #pragma unroll
    for (int off = 8; off >= 1; off >>= 1) rmL = fmaxf(rmL, __shfl_xor(rmL, off));
    float rsL = 0.f;
    if (anyv && rmL > NEGINF) {
      #pragma unroll
      for (int c = 0; c < 8; ++c) if (um >> c & 1u) rsL += __expf(xv[c] + wc[c] - rmL);
    }
    #pragma unroll
    for (int off = 8; off >= 1; off >>= 1) rsL += __shfl_xor(rsL, off);
    if (tc == 0) {
      rowGs[ct * NN + r] = rsG;
      rowLm[ct * NN + r] = rmL;
      rowLs[ct * NN + r] = rsL;
    }
  }
  __shared__ float shm[16][128];
  __shared__ float shs[16][128];
  #pragma unroll
  for (int c = 0; c < 8; ++c) { shm[tr][(tc << 3) + c] = cLm[c]; shs[tr][(tc << 3) + c] = cLs[c]; }
  __syncthreads();
  if (tid < 128) {
    float m = NEGINF, s = 0.f;
    #pragma unroll
    for (int g = 0; g < 16; ++g) lse_merge(m, s, shm[g][tid], shs[g][tid]);
    const int j = cbase + tid;
    if (j <= NN) { colLm[rt * LDA + j] = m; colLs[rt * LDA + j] = s; }
  }
  __syncthreads();
  #pragma unroll
  for (int c = 0; c < 8; ++c) shs[tr][(tc << 3) + c] = cGs[c];
  __syncthreads();
  if (tid < 128) {
    float s = 0.f;
    #pragma unroll
    for (int g = 0; g < 16; ++g) s += shs[g][tid];
    const int j = cbase + tid;
    if (j <= NN) colGs[rt * LDA + j] = s;
  }
}

__global__ void final_combine(const float* rowLm, const float* rowLs, const float* rowGs,
                              const float* colLm, const float* colLs, const float* colGs,
                              float* LSMrow, float* LBLm, float* LBLs,
                              float* LSMcol, float* LBTm, float* LBTs) {
  const int b = blockIdx.x;
  if (b < 16) {
    const int i = (b << 8) + threadIdx.x;
    float m = NEGINF, s = 0.f, sg = 0.f;
    for (int t = 0; t < 33; ++t) {
      lse_merge(m, s, rowLm[t * NN + i], rowLs[t * NN + i]);
      sg += rowGs[t * NN + i];
    }
    LBLm[i] = m; LBLs[i] = s;
    LSMrow[i] = __logf(sg);
  } else {
    const int j = ((b - 16) << 8) + threadIdx.x;
    if (j <= NN) {
      float m = NEGINF, s = 0.f, sg = 0.f;
      for (int t = 0; t < 32; ++t) {
        lse_merge(m, s, colLm[t * LDA + j], colLs[t * LDA + j]);
        sg += colGs[t * LDA + j];
      }
      LBTm[j] = m; LBTs[j] = s;
      LSMcol[j] = __logf(sg);
    }
  }
}

/* ------- final pass 2: KL sums (128x128 tiles, grid (33,32)) ------- */
__global__ __launch_bounds__(256) void loss_pass(const u16* S, const float* vvec,
                          const float* vtvec, const float* misc, const int* is_nc,
                          const float* LSMrow, const float* LBLm, const float* LBLs,
                          const float* LSMcol, const float* LBTm, const float* LBTs,
                          float* imgP, float* txtP) {
  const float a = misc[1], scale = misc[0];
  const int ct = blockIdx.x, rt = blockIdx.y;
  const int tid = threadIdx.x;
  const int tc = tid & 15, tr = tid >> 4;
  const int cbase = ct << 7, r0 = rt << 7;
  const int j0 = cbase + (tc << 3);
  const bool anyv = (j0 <= NN);
  float vcw[8], bm[8], bsi[8], cg[8]; unsigned jval = 0;
  #pragma unroll
  for (int c = 0; c < 8; ++c) {
    int j = j0 + c;
    vcw[c] = 0.f; bm[c] = 0.f; bsi[c] = 0.f; cg[c] = 0.f;
    if (j <= NN) {
      jval |= 1u << c;
      vcw[c] = vvec[j] * INVREG; bm[c] = LBTm[j]; bsi[c] = 1.f / LBTs[j]; cg[c] = LSMcol[j];
    }
  }
  float sImg = 0.f, sTxt = 0.f;
  for (int st = 0; st < 8; ++st) {
    const int r = r0 + (st << 4) + tr;
    if (anyv) {
      float raw[8];
      unpack8(*(const Q*)(S + (size_t)r * LDA + j0), raw);
      const bool ncr = (is_nc[r] != 0);
      const float vtr = vtvec[r] * INVREG;
      const float rm = LBLm[r], rsi = 1.f / LBLs[r], rg = LSMrow[r];
      #pragma unroll
      for (int c = 0; c < 8; ++c) {
        if (!(jval >> c & 1u)) continue;
        const int j = j0 + c;
        float xv = raw[c] * a;
        float lgt = scale * raw[c];
        bool unm = unmasked(j, r, ncr);
        bool lv = (j == NN) ? ncr : ((j == r) && !ncr);
        float rr = unm ? __expf(xv + vcw[c] - rm) * rsi : 0.f;
        float t = GAM * rr + (lv ? 0.2f : 0.f);
        if (t > 0.f) sImg += t * (__logf(t) - (lgt - rg));
        float r2 = unm ? __expf(xv + vtr - bm[c]) * bsi[c] : 0.f;
        float t2 = GAM * r2 + (lv ? 0.2f : 0.f);
        if (t2 > 0.f) sTxt += t2 * (__logf(t2) - (lgt - cg[c]));
      }
    }
  }
  sImg = blockReduce256(sImg);
  sTxt = blockReduce256(sTxt);
  if (tid == 0) { imgP[rt * 33 + ct] = sImg; txtP[rt * 33 + ct] = sTxt; }
}

__global__ void finish_kernel(const float* imgP, const float* txtP,
                              const float* misc, float* out) {
  float vi = 0.f, vtx = 0.f;
  for (int idx = threadIdx.x; idx < 1056; idx += 256) { vi += imgP[idx]; vtx += txtP[idx]; }
  vi = blockReduce256(vi);
  vtx = blockReduce256(vtx);
  if (threadIdx.x == 0) {
    float loss_img = vi / 4096.0f;
    float loss_txt = vtx / 4097.0f;
    float loss_ul = 0.5f * (loss_img + loss_txt);
    float loss_op = misc[4] / 4096.0f;
    if (vi == 0.f && vtx == 0.f) loss_ul = 777.0f;
    if (!(loss_ul == loss_ul))   loss_ul = 888.0f;
    out[0] = loss_ul;
    out[1] = loss_op;
  }
}

extern "C" void kernel_launch(void* const* d_in, const int* in_sizes, int n_in,
                              void* d_out, int out_size, void* d_ws, size_t ws_size,
                              hipStream_t stream) {
  (void)in_sizes; (void)n_in; (void)out_size;
  const u16* img = (const u16*)d_in[0];
  const u16* txt = (const u16*)d_in[1];
  const u16* tno = (const u16*)d_in[2];
  const u16* ls  = (const u16*)d_in[3];
  float* out = (float*)d_out;

  ContrastiveLoss_83391085019222_kernel<<<1, 64, 0, stream>>>(out);

  size_t off = 0;
  char* w = (char*)d_ws;
  u16* S; u16* Abf; u16* Bbf;
  float *rsA0, *rsA1, *csA0, *csA1, *rsB0, *rsB1, *csB0, *csB1, *errs;
  float *rowLm, *rowLs, *rowGs, *colLm, *colLs, *colGs;
  float *vecs, *preds, *colvals, *gmin, *opP;
  float *LSMrow, *LBLm, *LBLs, *LSMcol, *LBTm, *LBTs, *imgP, *txtP, *misc;
  int* is_nc; int* bar;
  #define ALLOC(ptr, type, nbytes) ptr = (type)(w + off); off = (off + (size_t)(nbytes) + 255) & ~(size_t)255
  ALLOC(S,      u16*,   (size_t)NN * LDA * 2);
  ALLOC(Abf,    u16*,   (size_t)NN * DD * 2);
  ALLOC(Bbf,    u16*,   (size_t)NN * DD * 2);
  ALLOC(rsA0,   float*, 4096 * 4);
  ALLOC(rsA1,   float*, 4096 * 4);
  ALLOC(csA0,   float*, 4104 * 4);
  ALLOC(csA1,   float*, 4104 * 4);
  ALLOC(rsB0,   float*, 4096 * 4);
  ALLOC(rsB1,   float*, 4096 * 4);
  ALLOC(csB0,   float*, 4104 * 4);
  ALLOC(csB1,   float*, 4104 * 4);
  ALLOC(errs,   float*, 256 * 4);
  ALLOC(rowLm,  float*, (size_t)33 * NN * 4);
  ALLOC(rowLs,  float*, (size_t)33 * NN * 4);
  ALLOC(rowGs,  float*, (size_t)33 * NN * 4);
  ALLOC(colLm,  float*, (size_t)32 * LDA * 4);
  ALLOC(colLs,  float*, (size_t)32 * LDA * 4);
  ALLOC(colGs,  float*, (size_t)32 * LDA * 4);
  ALLOC(vecs,   float*, 16400 * 4);
  ALLOC(preds,  float*, NN * 4);
  ALLOC(is_nc,  int*,   NN * 4);
  ALLOC(colvals,float*, NN * 4);
  ALLOC(gmin,   float*, 1024 * 4);
  ALLOC(opP,    float*, 1024 * 4);
  ALLOC(LSMrow, float*, NN * 4);
  ALLOC(LBLm,   float*, NN * 4);
  ALLOC(LBLs,   float*, NN * 4);
  ALLOC(LSMcol, float*, LDA * 4);
  ALLOC(LBTm,   float*, LDA * 4);
  ALLOC(LBTs,   float*, LDA * 4);
  ALLOC(imgP,   float*, 1056 * 4);
  ALLOC(txtP,   float*, 1056 * 4);
  ALLOC(bar,    int*,   4096);
  ALLOC(misc,   float*, 64);
  #undef ALLOC

  if (ws_size < off) {
    diag_kernel<<<1, 64, 0, stream>>>(out, -(float)(ws_size / 1000000.0),
                                      -(float)(off / 1000000.0));
    return;
  }

  float* uvec  = vecs;
  float* vvec  = vecs + 4096;
  float* utvec = vecs + 8200;
  float* vtvec = vecs + 12304;
  float* errs1 = errs;
  float* errs2 = errs + 128;

  detect_kernel<<<1, 64, 0, stream>>>(img, misc);
  cvt_kernel<<<2048, 256, 0, stream>>>(img, txt, Abf, Bbf, misc);
  init_kernel<<<65, 256, 0, stream>>>(ls, vecs, errs, rsA0, csA0, bar, misc);
  gemm_mfma<<<dim3(32, 32), 256, 0, stream>>>(Abf, Bbf, S, gmin);
  colvec_kernel<<<1024, 256, 0, stream>>>(img, txt, tno, S, colvals, opP, misc);
  reduce_kernel<<<1, 256, 0, stream>>>(gmin, colvals, opP, misc);

  preds_kernel<<<1024, 256, 0, stream>>>(S, misc, preds);
  rank_kernel<<<4096, 256, 0, stream>>>(preds, is_nc);

  /* persistent sinkhorn: 1024 blocks, 4/CU guaranteed by launch bounds */
  sink_persist<<<dim3(32, 32), 256, 0, stream>>>(S, misc, errs1, errs2,
      uvec, utvec, vvec, vtvec,
      rsA0, rsA1, csA0, csA1, rsB0, rsB1, csB0, csB1,
      is_nc, bar);

  final_pass<<<dim3(33, 32), 256, 0, stream>>>(S, vvec, vtvec, misc, is_nc,
                                               rowLm, rowLs, rowGs, colLm, colLs, colGs);
  final_combine<<<33, 256, 0, stream>>>(rowLm, rowLs, rowGs, colLm, colLs, colGs,
                                        LSMrow, LBLm, LBLs, LSMcol, LBTm, LBTs);
  loss_pass<<<dim3(33, 32), 256, 0, stream>>>(S, vvec, vtvec, misc, is_nc,
                                              LSMrow, LBLm, LBLs, LSMcol, LBTm, LBTs, imgP, txtP);
  finish_kernel<<<1, 256, 0, stream>>>(imgP, txtP, misc, out);
}

// Round 6
// 347.385 us; speedup vs baseline: 1.1875x; 1.1875x over previous
//

#include <hip/hip_runtime.h>
#include <hip/hip_bf16.h>

// ROUND 26 (round 25: 412.5 us REGRESSION; wave-parallel poll made all 1024
// blocks hammer the 32 arrival-counter lines -> poll/RMW contention, barrier
// 1.9 -> 3.6 us. Lesson: poll lines must be (a) separate from arrival lines,
// (b) fanned out so ~32 pollers/line max):
//  - gridbar reverted verbatim to the round-24 design (group counter ->
//    global counter -> per-group release flags; relaxed agent atomics;
//    monotonic; flags on separate lines). Proven 101 us sink_persist.
//  - everything else byte-identical to round 24 (346.8 us total).

#define NN 4096
#define LDA 4104          /* fp16 row stride for S (4097 padded to x8) */
#define DD 512
#define NCNUM 409         /* int(0.1*4096) */
#define REGc 0.03f
#define INVREG (1.0f/0.03f)
#define GAM 0.8f
#define THRESHc 1e-4f
#define LOGN 8.3177661667193433f   /* ln(4096) */
#define LOGM 8.3180102775477533f   /* ln(4097) */
#define NEGINF (-__builtin_inff())

typedef unsigned short u16;
typedef unsigned int u32;
typedef _Float16 f16;

struct alignas(16) Q  { u32 x, y, z, w; };
union H8 { Q q; f16 h[8]; };

typedef __attribute__((ext_vector_type(8))) short frag_ab;   /* 8 bf16 */
typedef __attribute__((ext_vector_type(4))) float frag_cd;   /* 4 f32  */

__device__ __forceinline__ float bf2f(u32 u) { return __uint_as_float(u << 16); }
__device__ __forceinline__ float bflo(u32 w) { return __uint_as_float(w << 16); }
__device__ __forceinline__ float bfhi(u32 w) { return __uint_as_float(w & 0xFFFF0000u); }
__device__ __forceinline__ u16 f2bf_rne(float f) {
  u32 b = __float_as_uint(f);
  b += 0x7FFFu + ((b >> 16) & 1u);
  return (u16)(b >> 16);
}
__device__ __forceinline__ u16 f2h_hw(float f) {
  union { f16 h; u16 u; } X; X.h = (f16)f; return X.u;
}
__device__ __forceinline__ float h2f_hw(u16 v) {
  union { u16 u; f16 h; } X; X.u = v; return (float)X.h;
}
__device__ __forceinline__ float exp2_fast(float x) {
#if __has_builtin(__builtin_amdgcn_exp2f)
  return __builtin_amdgcn_exp2f(x);
#else
  float r; asm("v_exp_f32 %0, %1" : "=v"(r) : "v"(x)); return r;
#endif
}
/* LLC-point (agent-scope, relaxed) load/store: no L2 invalidate/writeback */
__device__ __forceinline__ float ldu(const float* p) {
  return __hip_atomic_load(p, __ATOMIC_RELAXED, __HIP_MEMORY_SCOPE_AGENT);
}
__device__ __forceinline__ void stu(float* p, float v) {
  __hip_atomic_store(p, v, __ATOMIC_RELAXED, __HIP_MEMORY_SCOPE_AGENT);
}
/* async global->LDS, 16B per lane; lds base must be wave-uniform */
__device__ __forceinline__ void gload_lds16(const u16* g, u16* l) {
  __builtin_amdgcn_global_load_lds(
      (const __attribute__((address_space(1))) u32*)g,
      (__attribute__((address_space(3))) u32*)l, 16, 0, 0);
}
__device__ __forceinline__ void unpack8(Q q, float* x) {
  H8 u; u.q = q;
  #pragma unroll
  for (int c = 0; c < 8; ++c) x[c] = (float)u.h[c];
}
__device__ __forceinline__ void lse_merge(float& m, float& s, float om, float os) {
  float nm = fmaxf(m, om);
  if (nm == NEGINF) return;
  float acc = 0.f;
  if (s  > 0.f) acc += s  * __expf(m  - nm);
  if (os > 0.f) acc += os * __expf(om - nm);
  m = nm; s = acc;
}
__device__ __forceinline__ float blockReduce256(float v) {
  __shared__ float sh[4];
  #pragma unroll
  for (int off = 32; off >= 1; off >>= 1) v += __shfl_xor(v, off);
  int w = threadIdx.x >> 6;
  if ((threadIdx.x & 63) == 0) sh[w] = v;
  __syncthreads();
  float r = 0.f;
  if (threadIdx.x == 0) r = sh[0] + sh[1] + sh[2] + sh[3];
  __syncthreads();
  return r;
}

__global__ void ContrastiveLoss_83391085019222_kernel(float* out) {
  if (threadIdx.x == 0) { out[0] = 0.5f; out[1] = 0.5f; }
}
__global__ void diag_kernel(float* out, float a, float b) {
  if (threadIdx.x == 0) { out[0] = a; out[1] = b; }
}

/* ---- dtype autodetect: inputs are unit-normalized rows ---- */
__global__ void detect_kernel(const u16* img, float* misc) {
  const int lane = threadIdx.x;  /* 64 */
  float nb = 0.f, nf = 0.f;
  const float* fimg = (const float*)img;
  for (int c = lane * 8; c < lane * 8 + 8; ++c) {
    float xb = bf2f((u32)img[c]);
    nb += xb * xb;
    float xf = fimg[c];
    if (fabsf(xf) < 1e10f) nf += xf * xf; else nf += 1e10f;
  }
  #pragma unroll
  for (int off = 32; off >= 1; off >>= 1) { nb += __shfl_xor(nb, off); nf += __shfl_xor(nf, off); }
  if (lane == 0) {
    float db = fabsf(nb - 1.f);
    float df = fabsf(nf - 1.f);
    if (!(db == db)) db = 1e30f;
    if (!(df == df)) df = 1e30f;
    ((int*)misc)[10] = (df < db) ? 1 : 0;   /* 1 = float32 inputs */
  }
}

/* ---- convert img/txt to bf16 planes ---- */
__global__ void cvt_kernel(const u16* img, const u16* txt,
                           u16* Abf, u16* Bbf, const float* misc) {
  const int isF = ((const int*)misc)[10];
  const int t = blockIdx.x * 256 + threadIdx.x;
  const int base = t * 4;
  if (isF) {
    const float* fi = (const float*)img;
    const float* ft = (const float*)txt;
    ushort4 oa, ob;
    oa.x = f2bf_rne(fi[base+0]); oa.y = f2bf_rne(fi[base+1]);
    oa.z = f2bf_rne(fi[base+2]); oa.w = f2bf_rne(fi[base+3]);
    ob.x = f2bf_rne(ft[base+0]); ob.y = f2bf_rne(ft[base+1]);
    ob.z = f2bf_rne(ft[base+2]); ob.w = f2bf_rne(ft[base+3]);
    *(ushort4*)(Abf + base) = oa;
    *(ushort4*)(Bbf + base) = ob;
  } else {
    *(ushort4*)(Abf + base) = *(const ushort4*)(img + base);
    *(ushort4*)(Bbf + base) = *(const ushort4*)(txt + base);
  }
}

/* init: zero vecs(16400) + errs(256) + rsA0(4096) + csA0(4104) + bar(1024), scale */
__global__ void init_kernel(const u16* ls, float* vecs, float* errs,
                            float* rsA0, float* csA0, int* bar, float* misc) {
  int t = blockIdx.x * 256 + threadIdx.x;
  if (t < 16400) vecs[t] = 0.f;
  if (t < 256)  errs[t] = 0.f;
  if (t < 4096) rsA0[t] = 0.f;
  if (t < 4104) csA0[t] = 0.f;
  if (t < 1024) bar[t] = 0;
  if (t == 0) {
    const int isF = ((const int*)misc)[10];
    float lsv = isF ? ((const float*)ls)[0] : bf2f((u32)ls[0]);
    misc[0] = __expf(lsv);               /* scale = exp(logit_scale) */
  }
}

/* ------- MFMA GEMM (m97 structure): S = Abf x Bbf^T -> fp16 + min ------- */
__global__ __launch_bounds__(256) void gemm_mfma(const u16* Abf, const u16* Bbf,
                                                 u16* S, float* gmin) {
  __shared__ float red[256];
  __shared__ u16 ldsA[128 * 64];
  __shared__ u16 ldsB[128 * 64];
  const int tid = threadIdx.x;
  const int wave = tid >> 6, lane = tid & 63;
  const int wr = wave >> 1, wc = wave & 1;
  const int rb = (int)blockIdx.y * 128;
  const int cb = (int)blockIdx.x * 128;
  const int l15 = lane & 15, q = lane >> 4;
  const int srow = lane >> 3;          /* 0..7 row within 8-row issue group */
  const int scol = (lane & 7) * 8;     /* col element (x8, 16B) */

  frag_cd acc[4][4];
  #pragma unroll
  for (int i = 0; i < 4; ++i)
    #pragma unroll
    for (int j = 0; j < 4; ++j) acc[i][j] = (frag_cd){0.f, 0.f, 0.f, 0.f};

  for (int kt = 0; kt < DD; kt += 64) {
    __syncthreads();                   /* previous compute done before overwrite */
    #pragma unroll
    for (int i = 0; i < 4; ++i) {
      const int R = (wave * 4 + i) * 8;   /* wave-uniform 8-row group */
      gload_lds16(Abf + (size_t)(rb + R + srow) * DD + kt + scol, &ldsA[R * 64]);
      gload_lds16(Bbf + (size_t)(cb + R + srow) * DD + kt + scol, &ldsB[R * 64]);
    }
    __syncthreads();                   /* vmcnt(0) drain: tiles resident */
    #pragma unroll
    for (int s = 0; s < 2; ++s) {
      frag_ab af[4], bfr[4];
      #pragma unroll
      for (int t = 0; t < 4; ++t) {
        af[t]  = *(const frag_ab*)&ldsA[(wr * 64 + t * 16 + l15) * 64 + s * 32 + q * 8];
        bfr[t] = *(const frag_ab*)&ldsB[(wc * 64 + t * 16 + l15) * 64 + s * 32 + q * 8];
      }
      #pragma unroll
      for (int i = 0; i < 4; ++i)
        #pragma unroll
        for (int j = 0; j < 4; ++j)
          acc[i][j] = __builtin_amdgcn_mfma_f32_16x16x32_bf16(af[i], bfr[j], acc[i][j], 0, 0, 0);
    }
  }

  float lmin = 1e30f;
  #pragma unroll
  for (int i = 0; i < 4; ++i) {
    #pragma unroll
    for (int j = 0; j < 4; ++j) {
      #pragma unroll
      for (int r = 0; r < 4; ++r) {
        const int row = rb + wr * 64 + i * 16 + q * 4 + r;
        const int col = cb + wc * 64 + j * 16 + l15;
        u16 h = f2h_hw(acc[i][j][r]);
        lmin = fminf(lmin, h2f_hw(h));
        S[(size_t)row * LDA + col] = h;
      }
    }
  }
  red[tid] = lmin;
  __syncthreads();
  for (int sN = 128; sN >= 1; sN >>= 1) {
    if (tid < sN) red[tid] = fminf(red[tid], red[tid + sN]);
    __syncthreads();
  }
  if (tid == 0) gmin[blockIdx.y * 32 + blockIdx.x] = red[0];
}

/* ------- sims_no -> S col NN + loss_op partial ------- */
__global__ void colvec_kernel(const u16* img, const u16* txt, const u16* tno,
                              u16* S, float* colvals, float* opP, const float* misc) {
  __shared__ float shOp[4];
  const int isF = ((const int*)misc)[10];
  const int wv = threadIdx.x >> 6;
  const int row = (int)(blockIdx.x << 2) + wv;
  const int lane = threadIdx.x & 63;
  const size_t base = (size_t)row * DD + lane * 8;
  float xi[8], xt[8], xn[8];
  if (isF) {
    const float* fi = (const float*)img;
    const float* ft = (const float*)txt;
    const float* fn = (const float*)tno;
    #pragma unroll
    for (int c = 0; c < 8; ++c) { xi[c] = fi[base+c]; xt[c] = ft[base+c]; xn[c] = fn[base+c]; }
  } else {
    Q qi = *(const Q*)(img + base);
    Q qt = *(const Q*)(txt + base);
    Q qn = *(const Q*)(tno + base);
    xi[0]=bflo(qi.x); xi[1]=bfhi(qi.x); xi[2]=bflo(qi.y); xi[3]=bfhi(qi.y);
    xi[4]=bflo(qi.z); xi[5]=bfhi(qi.z); xi[6]=bflo(qi.w); xi[7]=bfhi(qi.w);
    xt[0]=bflo(qt.x); xt[1]=bfhi(qt.x); xt[2]=bflo(qt.y); xt[3]=bfhi(qt.y);
    xt[4]=bflo(qt.z); xt[5]=bfhi(qt.z); xt[6]=bflo(qt.w); xt[7]=bfhi(qt.w);
    xn[0]=bflo(qn.x); xn[1]=bfhi(qn.x); xn[2]=bflo(qn.y); xn[3]=bfhi(qn.y);
    xn[4]=bflo(qn.z); xn[5]=bfhi(qn.z); xn[6]=bflo(qn.w); xn[7]=bfhi(qn.w);
  }
  float sn = 0.f, cs = 0.f;
  #pragma unroll
  for (int c = 0; c < 8; ++c) { sn += xi[c]*xn[c]; cs += xt[c]*xn[c]; }
  #pragma unroll
  for (int off = 32; off >= 1; off >>= 1) { sn += __shfl_xor(sn, off); cs += __shfl_xor(cs, off); }
  if (lane == 0) {
    colvals[row] = sn;
    S[(size_t)row * LDA + NN] = f2h_hw(sn);
    shOp[wv] = fmaxf(cs + 0.2f, 0.f) + fmaxf(-0.7f - cs, 0.f);
  }
  __syncthreads();
  if (threadIdx.x == 0) opP[blockIdx.x] = shOp[0] + shOp[1] + shOp[2] + shOp[3];
}

__global__ void reduce_kernel(const float* gmin, const float* colvals,
                              const float* opP, float* misc) {
  __shared__ float smin[256];
  __shared__ float ssum[256];
  float mn = 1e30f, sm = 0.f;
  for (int i = threadIdx.x; i < 1024; i += 256) mn = fminf(mn, gmin[i]);
  for (int i = threadIdx.x; i < 4096; i += 256) mn = fminf(mn, h2f_hw(f2h_hw(colvals[i])));
  for (int i = threadIdx.x; i < 1024; i += 256) sm += opP[i];
  smin[threadIdx.x] = mn; ssum[threadIdx.x] = sm;
  __syncthreads();
  for (int sN = 128; sN >= 1; sN >>= 1) {
    if (threadIdx.x < sN) {
      smin[threadIdx.x] = fminf(smin[threadIdx.x], smin[threadIdx.x + sN]);
      ssum[threadIdx.x] += ssum[threadIdx.x + sN];
    }
    __syncthreads();
  }
  if (threadIdx.x == 0) {
    float maxC = 1.0f - smin[0];         /* max(1-S) = 1 - min(S) */
    float a = 1.0f / (maxC * REGc);
    misc[1] = a;
    misc[4] = ssum[0];
    misc[5] = __expf(-a);                /* ea */
    misc[6] = a * 1.4426950408889634f;   /* b = a*log2(e) for exp2 fast path */
  }
}

__global__ void preds_kernel(const u16* S, const float* misc, float* preds) {
  const int row = (int)(blockIdx.x << 2) + (int)(threadIdx.x >> 6);
  const int lane = threadIdx.x & 63;
  const float scale = misc[0];
  const u16* Sr = S + (size_t)row * LDA;
  float m = NEGINF, s = 0.f;
  for (int it = 0; it < 8; ++it) {
    const int j0 = (it << 9) + (lane << 3);
    float x[8];
    unpack8(*(const Q*)(Sr + j0), x);
    float lm = NEGINF;
    #pragma unroll
    for (int c = 0; c < 8; ++c) { x[c] *= scale; lm = fmaxf(lm, x[c]); }
    float lsum = 0.f;
    #pragma unroll
    for (int c = 0; c < 8; ++c) lsum += __expf(x[c] - lm);
    lse_merge(m, s, lm, lsum);
  }
  #pragma unroll
  for (int off = 32; off >= 1; off >>= 1) {
    float om = __shfl_xor(m, off), os = __shfl_xor(s, off);
    lse_merge(m, s, om, os);
  }
  if (lane == 0) {
    float sii = h2f_hw(Sr[row]);
    preds[row] = __expf(scale * sii - m) / s;
  }
}

/* ------- nc rank: one block per row ------- */
__global__ void rank_kernel(const float* preds, int* is_nc) {
  const int i = blockIdx.x;
  const float pv = preds[i];
  float cnt = 0.f;
  for (int k2 = threadIdx.x; k2 < NN; k2 += 256) {
    float pk = preds[k2];
    cnt += (pk < pv || (pk == pv && k2 < i)) ? 1.f : 0.f;
  }
  cnt = blockReduce256(cnt);
  if (threadIdx.x == 0) is_nc[i] = (cnt < (float)NCNUM) ? 1 : 0;
}

__device__ __forceinline__ bool unmasked(int j, int r, bool ncr) {
  return (j == NN) ? ncr : !((j == r) && ncr);
}

/* ------- fence-free monotonic tree barrier (round-24 proven design) -------
   32 groups x 32 blocks; 64B-padded counters; per-group release flags on
   SEPARATE lines from arrival counters (pollers never contend with RMWs;
   <=32 pollers per flag line). All ops relaxed agent-scope (LLC point).
   Monotonic, no resets. __syncthreads drains vmcnt -> prior device-scope
   atomics complete at LLC before the arrival RMW. */
__device__ __forceinline__ void gridbar(int* bar, int bid, int phase, bool& dead) {
  __syncthreads();
  if (threadIdx.x == 0 && !dead) {
    const int g = bid & 31;
    if (__hip_atomic_fetch_add(&bar[g << 4], 1, __ATOMIC_RELAXED,
                               __HIP_MEMORY_SCOPE_AGENT) == 32 * phase - 1) {
      if (__hip_atomic_fetch_add(&bar[32 << 4], 1, __ATOMIC_RELAXED,
                                 __HIP_MEMORY_SCOPE_AGENT) == 32 * phase - 1) {
        #pragma unroll
        for (int gg = 0; gg < 32; ++gg)
          __hip_atomic_store(&bar[(gg << 4) + 8], phase, __ATOMIC_RELAXED,
                             __HIP_MEMORY_SCOPE_AGENT);
      }
    }
    int spins = 0;
    while (__hip_atomic_load(&bar[(g << 4) + 8], __ATOMIC_RELAXED,
                             __HIP_MEMORY_SCOPE_AGENT) < phase) {
      __builtin_amdgcn_s_sleep(2);
      if (++spins > (1 << 21)) { dead = true; break; }   /* ~0.1s sticky cap */
    }
  }
  __syncthreads();
}

/* ------- one sinkhorn sub-step with cached E (gates passed in) ---- */
template<int RB, int FIN>
__device__ __forceinline__ void substep(
    float (&Ec)[8][8], int k,
    int c1, int c2, int c1p, int c2p,
    const float* prevRow, const float* prevCol,
    float* outRow, float* outCol,
    float* z1, float* z2, int nz1, int nz2,
    float* errs1, float* errs2,
    float* uvec, float* utvec, float* vvec, float* vtvec,
    float* shW1, float* shW2, float (*shAcc)[128], float* sh4096,
    float* se,
    float ea, int rt, int ct, int bid, int tid, int tc, int tr,
    int j0c, int r0, int cbase, bool isLast) {

  const int gRow = RB ? c2 : c1;
  const int gCol = RB ? c1 : c2;

  if (!FIN) {
    const int z = bid * 256 + tid;          /* 8200 < 262144: one shot */
    if (z < nz1) stu(&z1[z], 0.f);
    else if (z - nz1 < nz2) stu(&z2[z - nz1], 0.f);
  }

  /* speculative LLC loads of prev sums (overlap with zeroing) */
  float pr = 0.f, prN = 0.f;
  if (tid < 128) {
    pr = ldu(&prevRow[r0 + tid]);
  } else {
    pr = ldu(&prevCol[cbase + (tid - 128)]);
    if (isLast && tid == 128) prN = ldu(&prevCol[NN]);
  }

  float errd = 0.f;
  if (tid < 128) {
    const int i = r0 + tid;
    float w = 0.f;
    if (!RB) {
      if (!FIN && !gCol) w = (k == 0) ? ea : ea / (4096.0f * pr);
      if (ct == 0 && k >= 1 && !c2p) vtvec[i] = REGc * (-LOGN - __logf(pr));
    } else {
      if (!gCol) {
        w = ea / (4096.0f * pr);
        if (ct == 0) {
          float un = REGc * (-LOGN - __logf(pr));
          errd = fabsf(un - uvec[i]);
          uvec[i] = un;
        }
      }
    }
    shW2[tid] = w;
  } else {
    const int j = cbase + (tid - 128);
    float w = 0.f;
    if (!RB) {
      if (!FIN && !gRow) w = (k == 0) ? ea : ea / (4097.0f * pr);
      if (rt == 0 && k >= 1 && !c1p) vvec[j] = REGc * (-LOGM - __logf(pr));
    } else {
      if (!gRow) {
        w = ea / (4097.0f * pr);
        if (rt == 0) {
          float un = REGc * (-LOGM - __logf(pr));
          errd = fabsf(un - utvec[j]);
          utvec[j] = un;
        }
      }
    }
    shW1[tid - 128] = w;
    if (isLast && tid == 128) {        /* col 4096 sidecar weight */
      float w2 = 0.f;
      if (!RB) {
        if (!FIN && !gRow) w2 = (k == 0) ? ea : ea / (4097.0f * prN);
        if (rt == 0 && k >= 1 && !c1p) vvec[NN] = REGc * (-LOGM - __logf(prN));
      } else {
        if (!gRow) {
          w2 = ea / (4097.0f * prN);
          if (rt == 0) {
            float un = REGc * (-LOGM - __logf(prN));
            errd += fabsf(un - utvec[NN]);
            utvec[NN] = un;
          }
        }
      }
      shW1[128] = w2;
    }
  }
  __syncthreads();

  if (!FIN && !(gRow && gCol)) {
    float W1l[8];
    #pragma unroll
    for (int c = 0; c < 8; ++c) W1l[c] = shW1[j0c + c];
    float cs[8];
    #pragma unroll
    for (int c = 0; c < 8; ++c) cs[c] = 0.f;
    const float w4096 = isLast ? shW1[128] : 0.f;
    #pragma unroll
    for (int st = 0; st < 8; ++st) {
      const int rr = (st << 4) + tr;
      if (!gCol) {
        const float Wr = shW2[rr];
        #pragma unroll
        for (int c = 0; c < 8; ++c) cs[c] = fmaf(Ec[st][c], Wr, cs[c]);
      }
      if (!gRow) {
        float rs = 0.f;
        #pragma unroll
        for (int c = 0; c < 8; ++c) rs = fmaf(Ec[st][c], W1l[c], rs);
        #pragma unroll
        for (int off = 8; off >= 1; off >>= 1) rs += __shfl_xor(rs, off);
        if (tc == 0) {
          if (isLast) rs += sh4096[rr] * w4096;
          atomicAdd(&outRow[r0 + rr], rs);
        }
      }
    }
    if (!gCol) {
      #pragma unroll
      for (int c = 0; c < 8; ++c) shAcc[tr][j0c + c] = cs[c];
      __syncthreads();
      if (tid < 128) {
        float s2 = 0.f;
        #pragma unroll
        for (int g = 0; g < 16; ++g) s2 += shAcc[g][tid];
        atomicAdd(&outCol[cbase + tid], s2);
      }
      if (isLast && tid >= 128 && tid < 192) {   /* colsum for j=4096 */
        const int l = tid - 128;
        float s3 = sh4096[l] * shW2[l] + sh4096[l + 64] * shW2[l + 64];
        #pragma unroll
        for (int off = 32; off >= 1; off >>= 1) s3 += __shfl_xor(s3, off);
        if (l == 0) atomicAdd(&outCol[NN], s3);
      }
    }
  }

  if (RB) {
    float e2 = errd;
    #pragma unroll
    for (int off = 32; off >= 1; off >>= 1) e2 += __shfl_xor(e2, off);
    if ((tid & 63) == 0) se[tid >> 6] = e2;
    __syncthreads();
    if (tid == 0) {
      if (ct == 0) atomicAdd(&errs1[k], se[0] + se[1]);
      if (rt == 0) atomicAdd(&errs2[k], se[2] + se[3]);
    }
  }
}

/* ------- persistent sinkhorn: all iterations, E cached, early break ------- */
__global__ __launch_bounds__(256, 4) void sink_persist(
    const u16* S, const float* misc, float* errs1, float* errs2,
    float* uvec, float* utvec, float* vvec, float* vtvec,
    float* rsA0, float* rsA1, float* csA0, float* csA1,
    float* rsB0, float* rsB1, float* csB0, float* csB1,
    const int* is_nc, int* bar) {
  __shared__ float shW1[129];
  __shared__ float shW2[128];
  __shared__ float shAcc[16][128];
  __shared__ float sh4096[128];
  __shared__ int   shG[4];
  __shared__ float se[4];

  const int tid = threadIdx.x;
  const int rt = blockIdx.x, ct = blockIdx.y;
  const int bid = ct * 32 + rt;
  const int cbase = ct << 7, r0 = rt << 7;
  const float a = misc[1], ea = misc[5], b = misc[6];
  const int tc = tid & 15, tr = tid >> 4;
  const int j0c = tc << 3;
  const bool isLast = (ct == 31);

  /* ---- build E tile in registers, masks baked in ---- */
  float Ec[8][8];
  if (rt != ct) {
    #pragma unroll
    for (int st = 0; st < 8; ++st) {
      const int rr = (st << 4) + tr;
      H8 hh; hh.q = *(const Q*)(S + (size_t)(r0 + rr) * LDA + cbase + j0c);
      #pragma unroll
      for (int c = 0; c < 8; ++c) Ec[st][c] = exp2_fast((float)hh.h[c] * b);
    }
  } else {
    #pragma unroll
    for (int st = 0; st < 8; ++st) {
      const int rr = (st << 4) + tr;
      const int r = r0 + rr;
      float xv[8];
      unpack8(*(const Q*)(S + (size_t)r * LDA + cbase + j0c), xv);
      const bool ncr = (is_nc[r] != 0);
      #pragma unroll
      for (int c = 0; c < 8; ++c) {
        float e = __expf(xv[c] * a);
        if ((j0c + c == rr) && ncr) e = 0.f;   /* diag mask (cbase==r0) */
        Ec[st][c] = e;
      }
    }
  }
  if (isLast && tid < 128) {
    const int r = r0 + tid;
    float x = h2f_hw(S[(size_t)r * LDA + NN]);
    sh4096[tid] = (is_nc[r] != 0) ? __expf(x * a) : 0.f;
  }
  __syncthreads();

  bool dead = false;
  int phase = 0;
  for (int k = 0; k < 100; ++k) {
    const int p = k & 1;
    const int q2 = 1 - p;
    const int pm = (k > 0) ? q2 : 0;
    /* gates for iteration k (identical for substeps A and B) */
    if (tid < 4) {
      const int kk = k - 1 - (tid >> 1);
      const float* ep = (tid & 1) ? errs2 : errs1;
      shG[tid] = (kk >= 0) && (ldu(&ep[kk]) < THRESHc);
    }
    __syncthreads();
    const int c1 = shG[0], c2 = shG[1], c1p = shG[2], c2p = shG[3];
    if (c1 && c2 && c1p && c2p) break;   /* remaining substeps provably no-op */

    substep<0, 0>(Ec, k, c1, c2, c1p, c2p,
        pm ? rsB1 : rsB0, pm ? csB1 : csB0,
        p ? rsA1 : rsA0, p ? csA1 : csA0,
        p ? csB1 : csB0, p ? rsB1 : rsB0, 4104, 4096,
        errs1, errs2, uvec, utvec, vvec, vtvec,
        shW1, shW2, shAcc, sh4096, se,
        ea, rt, ct, bid, tid, tc, tr, j0c, r0, cbase, isLast);
    gridbar(bar, bid, ++phase, dead);

    substep<1, 0>(Ec, k, c1, c2, c1p, c2p,
        p ? rsA1 : rsA0, p ? csA1 : csA0,
        p ? rsB1 : rsB0, p ? csB1 : csB0,
        q2 ? rsA1 : rsA0, q2 ? csA1 : csA0, 4096, 4104,
        errs1, errs2, uvec, utvec, vvec, vtvec,
        shW1, shW2, shAcc, sh4096, se,
        ea, rt, ct, bid, tid, tc, tr, j0c, r0, cbase, isLast);
    gridbar(bar, bid, ++phase, dead);
  }

  /* final weight-only step (k=100); gates for k=100 (all-true if broken) */
  if (tid < 4) {
    const int kk = 99 - (tid >> 1);
    const float* ep = (tid & 1) ? errs2 : errs1;
    shG[tid] = (ldu(&ep[kk]) < THRESHc);
  }
  __syncthreads();
  substep<0, 1>(Ec, 100, shG[0], shG[1], shG[2], shG[3],
      rsB1, csB1, rsA0, csA0, rsA0, csA0, 0, 0,
      errs1, errs2, uvec, utvec, vvec, vtvec,
      shW1, shW2, shAcc, sh4096, se,
      ea, rt, ct, bid, tid, tc, tr, j0c, r0, cbase, isLast);
}

/* ------- final pass 1 (128x128 tiles, grid (33,32)) ------- */
__global__ __launch_bounds__(256) void final_pass(const u16* S, const float* vvec,
                           const float* vtvec, const float* misc, const int* is_nc,
                           float* rowLm, float* rowLs, float* rowGs,
                           float* colLm, float* colLs, float* colGs) {
  const float a = misc[1], scale = misc[0];
  const int ct = blockIdx.x, rt = blockIdx.y;
  const int tid = threadIdx.x;
  const int tc = tid & 15, tr = tid >> 4;
  const int cbase = ct << 7, r0 = rt << 7;
  const int j0 = cbase + (tc << 3);
  const bool anyv = (j0 <= NN);
  float wc[8]; unsigned jval = 0;
  #pragma unroll
  for (int c = 0; c < 8; ++c) {
    int j = j0 + c;
    wc[c] = 0.f;
    if (j <= NN) { jval |= 1u << c; wc[c] = vvec[j] * INVREG; }
  }
  float cLm[8], cLs[8], cGs[8];
  #pragma unroll
  for (int c = 0; c < 8; ++c) { cLm[c] = NEGINF; cLs[c] = 0.f; cGs[c] = 0.f; }
  for (int st = 0; st < 8; ++st) {
    const int r = r0 + (st << 4) + tr;
    float xv[8], lg[8]; unsigned um = 0;
    #pragma unroll
    for (int c = 0; c < 8; ++c) { xv[c] = 0.f; lg[c] = 0.f; }
    if (anyv) {
      float raw[8];
      unpack8(*(const Q*)(S + (size_t)r * LDA + j0), raw);
      const bool ncr = (is_nc[r] != 0);
      const float vtr = vtvec[r] * INVREG;
      #pragma unroll
      for (int c = 0; c < 8; ++c) {
        if (!(jval >> c & 1u)) continue;
        xv[c] = raw[c] * a;
        lg[c] = scale * raw[c];
        cGs[c] += __expf(lg[c]);
        if (unmasked(j0 + c, r, ncr)) {
          um |= 1u << c;
          float e2 = xv[c] + vtr;
          float nm = fmaxf(cLm[c], e2);
          cLs[c] = cLs[c] * __expf(cLm[c] - nm) + __expf(e2 - nm);
          cLm[c] = nm;
        }
      }
    }
    float rsG = 0.f;
    if (anyv) {
      #pragma unroll
      for (int c = 0; c < 8; ++c) if (jval >> c & 1u) rsG += __expf(lg[c]);
    }
    #pragma unroll
    for (int off = 8; off >= 1; off >>= 1) rsG += __shfl_xor(rsG, off);
    float rmL = NEGINF;
    if (anyv) {
      #pragma unroll
      for (int c = 0; c < 8; ++c) if (um >> c & 1u) rmL = fmaxf(rmL, xv[c] + wc[c]);
    }
    #pragma unroll
    for (int off = 8; off >= 1; off >>= 1) rmL = fmaxf(rmL, __shfl_xor(rmL, off));
    float rsL = 0.f;
    if (anyv && rmL > NEGINF) {
      #pragma unroll
      for (int c = 0; c < 8; ++c) if (um >> c & 1u) rsL += __expf(xv[c] + wc[c] - rmL);
    }
    #pragma unroll
    for (int off = 8; off >= 1; off >>= 1) rsL += __shfl_xor(rsL, off);
    if (tc == 0) {
      rowGs[ct * NN + r] = rsG;
      rowLm[ct * NN + r] = rmL;
      rowLs[ct * NN + r] = rsL;
    }
  }
  __shared__ float shm[16][128];
  __shared__ float shs[16][128];
  #pragma unroll
  for (int c = 0; c < 8; ++c) { shm[tr][(tc << 3) + c] = cLm[c]; shs[tr][(tc << 3) + c] = cLs[c]; }
  __syncthreads();
  if (tid < 128) {
    float m = NEGINF, s = 0.f;
    #pragma unroll
    for (int g = 0; g < 16; ++g) lse_merge(m, s, shm[g][tid], shs[g][tid]);
    const int j = cbase + tid;
    if (j <= NN) { colLm[rt * LDA + j] = m; colLs[rt * LDA + j] = s; }
  }
  __syncthreads();
  #pragma unroll
  for (int c = 0; c < 8; ++c) shs[tr][(tc << 3) + c] = cGs[c];
  __syncthreads();
  if (tid < 128) {
    float s = 0.f;
    #pragma unroll
    for (int g = 0; g < 16; ++g) s += shs[g][tid];
    const int j = cbase + tid;
    if (j <= NN) colGs[rt * LDA + j] = s;
  }
}

__global__ void final_combine(const float* rowLm, const float* rowLs, const float* rowGs,
                              const float* colLm, const float* colLs, const float* colGs,
                              float* LSMrow, float* LBLm, float* LBLs,
                              float* LSMcol, float* LBTm, float* LBTs) {
  const int b = blockIdx.x;
  if (b < 16) {
    const int i = (b << 8) + threadIdx.x;
    float m = NEGINF, s = 0.f, sg = 0.f;
    for (int t = 0; t < 33; ++t) {
      lse_merge(m, s, rowLm[t * NN + i], rowLs[t * NN + i]);
      sg += rowGs[t * NN + i];
    }
    LBLm[i] = m; LBLs[i] = s;
    LSMrow[i] = __logf(sg);
  } else {
    const int j = ((b - 16) << 8) + threadIdx.x;
    if (j <= NN) {
      float m = NEGINF, s = 0.f, sg = 0.f;
      for (int t = 0; t < 32; ++t) {
        lse_merge(m, s, colLm[t * LDA + j], colLs[t * LDA + j]);
        sg += colGs[t * LDA + j];
      }
      LBTm[j] = m; LBTs[j] = s;
      LSMcol[j] = __logf(sg);
    }
  }
}

/* ------- final pass 2: KL sums (128x128 tiles, grid (33,32)) ------- */
__global__ __launch_bounds__(256) void loss_pass(const u16* S, const float* vvec,
                          const float* vtvec, const float* misc, const int* is_nc,
                          const float* LSMrow, const float* LBLm, const float* LBLs,
                          const float* LSMcol, const float* LBTm, const float* LBTs,
                          float* imgP, float* txtP) {
  const float a = misc[1], scale = misc[0];
  const int ct = blockIdx.x, rt = blockIdx.y;
  const int tid = threadIdx.x;
  const int tc = tid & 15, tr = tid >> 4;
  const int cbase = ct << 7, r0 = rt << 7;
  const int j0 = cbase + (tc << 3);
  const bool anyv = (j0 <= NN);
  float vcw[8], bm[8], bsi[8], cg[8]; unsigned jval = 0;
  #pragma unroll
  for (int c = 0; c < 8; ++c) {
    int j = j0 + c;
    vcw[c] = 0.f; bm[c] = 0.f; bsi[c] = 0.f; cg[c] = 0.f;
    if (j <= NN) {
      jval |= 1u << c;
      vcw[c] = vvec[j] * INVREG; bm[c] = LBTm[j]; bsi[c] = 1.f / LBTs[j]; cg[c] = LSMcol[j];
    }
  }
  float sImg = 0.f, sTxt = 0.f;
  for (int st = 0; st < 8; ++st) {
    const int r = r0 + (st << 4) + tr;
    if (anyv) {
      float raw[8];
      unpack8(*(const Q*)(S + (size_t)r * LDA + j0), raw);
      const bool ncr = (is_nc[r] != 0);
      const float vtr = vtvec[r] * INVREG;
      const float rm = LBLm[r], rsi = 1.f / LBLs[r], rg = LSMrow[r];
      #pragma unroll
      for (int c = 0; c < 8; ++c) {
        if (!(jval >> c & 1u)) continue;
        const int j = j0 + c;
        float xv = raw[c] * a;
        float lgt = scale * raw[c];
        bool unm = unmasked(j, r, ncr);
        bool lv = (j == NN) ? ncr : ((j == r) && !ncr);
        float rr = unm ? __expf(xv + vcw[c] - rm) * rsi : 0.f;
        float t = GAM * rr + (lv ? 0.2f : 0.f);
        if (t > 0.f) sImg += t * (__logf(t) - (lgt - rg));
        float r2 = unm ? __expf(xv + vtr - bm[c]) * bsi[c] : 0.f;
        float t2 = GAM * r2 + (lv ? 0.2f : 0.f);
        if (t2 > 0.f) sTxt += t2 * (__logf(t2) - (lgt - cg[c]));
      }
    }
  }
  sImg = blockReduce256(sImg);
  sTxt = blockReduce256(sTxt);
  if (tid == 0) { imgP[rt * 33 + ct] = sImg; txtP[rt * 33 + ct] = sTxt; }
}

__global__ void finish_kernel(const float* imgP, const float* txtP,
                              const float* misc, float* out) {
  float vi = 0.f, vtx = 0.f;
  for (int idx = threadIdx.x; idx < 1056; idx += 256) { vi += imgP[idx]; vtx += txtP[idx]; }
  vi = blockReduce256(vi);
  vtx = blockReduce256(vtx);
  if (threadIdx.x == 0) {
    float loss_img = vi / 4096.0f;
    float loss_txt = vtx / 4097.0f;
    float loss_ul = 0.5f * (loss_img + loss_txt);
    float loss_op = misc[4] / 4096.0f;
    if (vi == 0.f && vtx == 0.f) loss_ul = 777.0f;
    if (!(loss_ul == loss_ul))   loss_ul = 888.0f;
    out[0] = loss_ul;
    out[1] = loss_op;
  }
}

extern "C" void kernel_launch(void* const* d_in, const int* in_sizes, int n_in,
                              void* d_out, int out_size, void* d_ws, size_t ws_size,
                              hipStream_t stream) {
  (void)in_sizes; (void)n_in; (void)out_size;
  const u16* img = (const u16*)d_in[0];
  const u16* txt = (const u16*)d_in[1];
  const u16* tno = (const u16*)d_in[2];
  const u16* ls  = (const u16*)d_in[3];
  float* out = (float*)d_out;

  ContrastiveLoss_83391085019222_kernel<<<1, 64, 0, stream>>>(out);

  size_t off = 0;
  char* w = (char*)d_ws;
  u16* S; u16* Abf; u16* Bbf;
  float *rsA0, *rsA1, *csA0, *csA1, *rsB0, *rsB1, *csB0, *csB1, *errs;
  float *rowLm, *rowLs, *rowGs, *colLm, *colLs, *colGs;
  float *vecs, *preds, *colvals, *gmin, *opP;
  float *LSMrow, *LBLm, *LBLs, *LSMcol, *LBTm, *LBTs, *imgP, *txtP, *misc;
  int* is_nc; int* bar;
  #define ALLOC(ptr, type, nbytes) ptr = (type)(w + off); off = (off + (size_t)(nbytes) + 255) & ~(size_t)255
  ALLOC(S,      u16*,   (size_t)NN * LDA * 2);
  ALLOC(Abf,    u16*,   (size_t)NN * DD * 2);
  ALLOC(Bbf,    u16*,   (size_t)NN * DD * 2);
  ALLOC(rsA0,   float*, 4096 * 4);
  ALLOC(rsA1,   float*, 4096 * 4);
  ALLOC(csA0,   float*, 4104 * 4);
  ALLOC(csA1,   float*, 4104 * 4);
  ALLOC(rsB0,   float*, 4096 * 4);
  ALLOC(rsB1,   float*, 4096 * 4);
  ALLOC(csB0,   float*, 4104 * 4);
  ALLOC(csB1,   float*, 4104 * 4);
  ALLOC(errs,   float*, 256 * 4);
  ALLOC(rowLm,  float*, (size_t)33 * NN * 4);
  ALLOC(rowLs,  float*, (size_t)33 * NN * 4);
  ALLOC(rowGs,  float*, (size_t)33 * NN * 4);
  ALLOC(colLm,  float*, (size_t)32 * LDA * 4);
  ALLOC(colLs,  float*, (size_t)32 * LDA * 4);
  ALLOC(colGs,  float*, (size_t)32 * LDA * 4);
  ALLOC(vecs,   float*, 16400 * 4);
  ALLOC(preds,  float*, NN * 4);
  ALLOC(is_nc,  int*,   NN * 4);
  ALLOC(colvals,float*, NN * 4);
  ALLOC(gmin,   float*, 1024 * 4);
  ALLOC(opP,    float*, 1024 * 4);
  ALLOC(LSMrow, float*, NN * 4);
  ALLOC(LBLm,   float*, NN * 4);
  ALLOC(LBLs,   float*, NN * 4);
  ALLOC(LSMcol, float*, LDA * 4);
  ALLOC(LBTm,   float*, LDA * 4);
  ALLOC(LBTs,   float*, LDA * 4);
  ALLOC(imgP,   float*, 1056 * 4);
  ALLOC(txtP,   float*, 1056 * 4);
  ALLOC(bar,    int*,   4096);
  ALLOC(misc,   float*, 64);
  #undef ALLOC

  if (ws_size < off) {
    diag_kernel<<<1, 64, 0, stream>>>(out, -(float)(ws_size / 1000000.0),
                                      -(float)(off / 1000000.0));
    return;
  }

  float* uvec  = vecs;
  float* vvec  = vecs + 4096;
  float* utvec = vecs + 8200;
  float* vtvec = vecs + 12304;
  float* errs1 = errs;
  float* errs2 = errs + 128;

  detect_kernel<<<1, 64, 0, stream>>>(img, misc);
  cvt_kernel<<<2048, 256, 0, stream>>>(img, txt, Abf, Bbf, misc);
  init_kernel<<<65, 256, 0, stream>>>(ls, vecs, errs, rsA0, csA0, bar, misc);
  gemm_mfma<<<dim3(32, 32), 256, 0, stream>>>(Abf, Bbf, S, gmin);
  colvec_kernel<<<1024, 256, 0, stream>>>(img, txt, tno, S, colvals, opP, misc);
  reduce_kernel<<<1, 256, 0, stream>>>(gmin, colvals, opP, misc);

  preds_kernel<<<1024, 256, 0, stream>>>(S, misc, preds);
  rank_kernel<<<4096, 256, 0, stream>>>(preds, is_nc);

  /* persistent sinkhorn: 1024 blocks, 4/CU guaranteed by launch bounds */
  sink_persist<<<dim3(32, 32), 256, 0, stream>>>(S, misc, errs1, errs2,
      uvec, utvec, vvec, vtvec,
      rsA0, rsA1, csA0, csA1, rsB0, rsB1, csB0, csB1,
      is_nc, bar);

  final_pass<<<dim3(33, 32), 256, 0, stream>>>(S, vvec, vtvec, misc, is_nc,
                                               rowLm, rowLs, rowGs, colLm, colLs, colGs);
  final_combine<<<33, 256, 0, stream>>>(rowLm, rowLs, rowGs, colLm, colLs, colGs,
                                        LSMrow, LBLm, LBLs, LSMcol, LBTm, LBTs);
  loss_pass<<<dim3(33, 32), 256, 0, stream>>>(S, vvec, vtvec, misc, is_nc,
                                              LSMrow, LBLm, LBLs, LSMcol, LBTm, LBTs, imgP, txtP);
  finish_kernel<<<1, 256, 0, stream>>>(imgP, txtP, misc, out);
}

// Round 8
// 340.705 us; speedup vs baseline: 1.2108x; 1.0196x over previous
//

#include <hip/hip_runtime.h>
#include <hip/hip_bf16.h>

// ROUND 28 (round 27 never executed: container failed at acquire, no timing
// data in the result -> infra flake, kernel unimplicated. Resubmitting the
// r27 kernel byte-identical):
//  - sink loop: gate-load (errs) issued CONCURRENTLY with substep A's
//    prev-sum loads (one syncthreads waits for both).
//  - final_pass + final_combine + loss_pass + finish FUSED into the tail of
//    sink_persist (4 extra gridbars). ct==31 blocks absorb the old ct==32
//    sidecar tiles with thread-pattern-identical code (bit-exact).
//    combine parallelized to 8193 1-thread outputs over 1024 blocks.
//  - 14 dispatches -> 10.

#define NN 4096
#define LDA 4104          /* fp16 row stride for S (4097 padded to x8) */
#define DD 512
#define NCNUM 409         /* int(0.1*4096) */
#define REGc 0.03f
#define INVREG (1.0f/0.03f)
#define GAM 0.8f
#define THRESHc 1e-4f
#define LOGN 8.3177661667193433f   /* ln(4096) */
#define LOGM 8.3180102775477533f   /* ln(4097) */
#define NEGINF (-__builtin_inff())

typedef unsigned short u16;
typedef unsigned int u32;
typedef _Float16 f16;

struct alignas(16) Q  { u32 x, y, z, w; };
union H8 { Q q; f16 h[8]; };

typedef __attribute__((ext_vector_type(8))) short frag_ab;   /* 8 bf16 */
typedef __attribute__((ext_vector_type(4))) float frag_cd;   /* 4 f32  */

__device__ __forceinline__ float bf2f(u32 u) { return __uint_as_float(u << 16); }
__device__ __forceinline__ float bflo(u32 w) { return __uint_as_float(w << 16); }
__device__ __forceinline__ float bfhi(u32 w) { return __uint_as_float(w & 0xFFFF0000u); }
__device__ __forceinline__ u16 f2bf_rne(float f) {
  u32 b = __float_as_uint(f);
  b += 0x7FFFu + ((b >> 16) & 1u);
  return (u16)(b >> 16);
}
__device__ __forceinline__ u16 f2h_hw(float f) {
  union { f16 h; u16 u; } X; X.h = (f16)f; return X.u;
}
__device__ __forceinline__ float h2f_hw(u16 v) {
  union { u16 u; f16 h; } X; X.u = v; return (float)X.h;
}
__device__ __forceinline__ float exp2_fast(float x) {
#if __has_builtin(__builtin_amdgcn_exp2f)
  return __builtin_amdgcn_exp2f(x);
#else
  float r; asm("v_exp_f32 %0, %1" : "=v"(r) : "v"(x)); return r;
#endif
}
/* LLC-point (agent-scope, relaxed) load/store: no L2 invalidate/writeback */
__device__ __forceinline__ float ldu(const float* p) {
  return __hip_atomic_load(p, __ATOMIC_RELAXED, __HIP_MEMORY_SCOPE_AGENT);
}
__device__ __forceinline__ void stu(float* p, float v) {
  __hip_atomic_store(p, v, __ATOMIC_RELAXED, __HIP_MEMORY_SCOPE_AGENT);
}
/* async global->LDS, 16B per lane; lds base must be wave-uniform */
__device__ __forceinline__ void gload_lds16(const u16* g, u16* l) {
  __builtin_amdgcn_global_load_lds(
      (const __attribute__((address_space(1))) u32*)g,
      (__attribute__((address_space(3))) u32*)l, 16, 0, 0);
}
__device__ __forceinline__ void unpack8(Q q, float* x) {
  H8 u; u.q = q;
  #pragma unroll
  for (int c = 0; c < 8; ++c) x[c] = (float)u.h[c];
}
__device__ __forceinline__ void lse_merge(float& m, float& s, float om, float os) {
  float nm = fmaxf(m, om);
  if (nm == NEGINF) return;
  float acc = 0.f;
  if (s  > 0.f) acc += s  * __expf(m  - nm);
  if (os > 0.f) acc += os * __expf(om - nm);
  m = nm; s = acc;
}
__device__ __forceinline__ float blockReduce256(float v) {
  __shared__ float sh[4];
  #pragma unroll
  for (int off = 32; off >= 1; off >>= 1) v += __shfl_xor(v, off);
  int w = threadIdx.x >> 6;
  if ((threadIdx.x & 63) == 0) sh[w] = v;
  __syncthreads();
  float r = 0.f;
  if (threadIdx.x == 0) r = sh[0] + sh[1] + sh[2] + sh[3];
  __syncthreads();
  return r;
}

__global__ void ContrastiveLoss_83391085019222_kernel(float* out) {
  if (threadIdx.x == 0) { out[0] = 0.5f; out[1] = 0.5f; }
}
__global__ void diag_kernel(float* out, float a, float b) {
  if (threadIdx.x == 0) { out[0] = a; out[1] = b; }
}

/* ---- dtype autodetect: inputs are unit-normalized rows ---- */
__global__ void detect_kernel(const u16* img, float* misc) {
  const int lane = threadIdx.x;  /* 64 */
  float nb = 0.f, nf = 0.f;
  const float* fimg = (const float*)img;
  for (int c = lane * 8; c < lane * 8 + 8; ++c) {
    float xb = bf2f((u32)img[c]);
    nb += xb * xb;
    float xf = fimg[c];
    if (fabsf(xf) < 1e10f) nf += xf * xf; else nf += 1e10f;
  }
  #pragma unroll
  for (int off = 32; off >= 1; off >>= 1) { nb += __shfl_xor(nb, off); nf += __shfl_xor(nf, off); }
  if (lane == 0) {
    float db = fabsf(nb - 1.f);
    float df = fabsf(nf - 1.f);
    if (!(db == db)) db = 1e30f;
    if (!(df == df)) df = 1e30f;
    ((int*)misc)[10] = (df < db) ? 1 : 0;   /* 1 = float32 inputs */
  }
}

/* ---- convert img/txt to bf16 planes ---- */
__global__ void cvt_kernel(const u16* img, const u16* txt,
                           u16* Abf, u16* Bbf, const float* misc) {
  const int isF = ((const int*)misc)[10];
  const int t = blockIdx.x * 256 + threadIdx.x;
  const int base = t * 4;
  if (isF) {
    const float* fi = (const float*)img;
    const float* ft = (const float*)txt;
    ushort4 oa, ob;
    oa.x = f2bf_rne(fi[base+0]); oa.y = f2bf_rne(fi[base+1]);
    oa.z = f2bf_rne(fi[base+2]); oa.w = f2bf_rne(fi[base+3]);
    ob.x = f2bf_rne(ft[base+0]); ob.y = f2bf_rne(ft[base+1]);
    ob.z = f2bf_rne(ft[base+2]); ob.w = f2bf_rne(ft[base+3]);
    *(ushort4*)(Abf + base) = oa;
    *(ushort4*)(Bbf + base) = ob;
  } else {
    *(ushort4*)(Abf + base) = *(const ushort4*)(img + base);
    *(ushort4*)(Bbf + base) = *(const ushort4*)(txt + base);
  }
}

/* init: zero vecs(16400) + errs(256) + rsA0(4096) + csA0(4104) + bar(1024), scale */
__global__ void init_kernel(const u16* ls, float* vecs, float* errs,
                            float* rsA0, float* csA0, int* bar, float* misc) {
  int t = blockIdx.x * 256 + threadIdx.x;
  if (t < 16400) vecs[t] = 0.f;
  if (t < 256)  errs[t] = 0.f;
  if (t < 4096) rsA0[t] = 0.f;
  if (t < 4104) csA0[t] = 0.f;
  if (t < 1024) bar[t] = 0;
  if (t == 0) {
    const int isF = ((const int*)misc)[10];
    float lsv = isF ? ((const float*)ls)[0] : bf2f((u32)ls[0]);
    misc[0] = __expf(lsv);               /* scale = exp(logit_scale) */
  }
}

/* ------- MFMA GEMM (m97 structure): S = Abf x Bbf^T -> fp16 + min ------- */
__global__ __launch_bounds__(256) void gemm_mfma(const u16* Abf, const u16* Bbf,
                                                 u16* S, float* gmin) {
  __shared__ float red[256];
  __shared__ u16 ldsA[128 * 64];
  __shared__ u16 ldsB[128 * 64];
  const int tid = threadIdx.x;
  const int wave = tid >> 6, lane = tid & 63;
  const int wr = wave >> 1, wc = wave & 1;
  const int rb = (int)blockIdx.y * 128;
  const int cb = (int)blockIdx.x * 128;
  const int l15 = lane & 15, q = lane >> 4;
  const int srow = lane >> 3;          /* 0..7 row within 8-row issue group */
  const int scol = (lane & 7) * 8;     /* col element (x8, 16B) */

  frag_cd acc[4][4];
  #pragma unroll
  for (int i = 0; i < 4; ++i)
    #pragma unroll
    for (int j = 0; j < 4; ++j) acc[i][j] = (frag_cd){0.f, 0.f, 0.f, 0.f};

  for (int kt = 0; kt < DD; kt += 64) {
    __syncthreads();                   /* previous compute done before overwrite */
    #pragma unroll
    for (int i = 0; i < 4; ++i) {
      const int R = (wave * 4 + i) * 8;   /* wave-uniform 8-row group */
      gload_lds16(Abf + (size_t)(rb + R + srow) * DD + kt + scol, &ldsA[R * 64]);
      gload_lds16(Bbf + (size_t)(cb + R + srow) * DD + kt + scol, &ldsB[R * 64]);
    }
    __syncthreads();                   /* vmcnt(0) drain: tiles resident */
    #pragma unroll
    for (int s = 0; s < 2; ++s) {
      frag_ab af[4], bfr[4];
      #pragma unroll
      for (int t = 0; t < 4; ++t) {
        af[t]  = *(const frag_ab*)&ldsA[(wr * 64 + t * 16 + l15) * 64 + s * 32 + q * 8];
        bfr[t] = *(const frag_ab*)&ldsB[(wc * 64 + t * 16 + l15) * 64 + s * 32 + q * 8];
      }
      #pragma unroll
      for (int i = 0; i < 4; ++i)
        #pragma unroll
        for (int j = 0; j < 4; ++j)
          acc[i][j] = __builtin_amdgcn_mfma_f32_16x16x32_bf16(af[i], bfr[j], acc[i][j], 0, 0, 0);
    }
  }

  float lmin = 1e30f;
  #pragma unroll
  for (int i = 0; i < 4; ++i) {
    #pragma unroll
    for (int j = 0; j < 4; ++j) {
      #pragma unroll
      for (int r = 0; r < 4; ++r) {
        const int row = rb + wr * 64 + i * 16 + q * 4 + r;
        const int col = cb + wc * 64 + j * 16 + l15;
        u16 h = f2h_hw(acc[i][j][r]);
        lmin = fminf(lmin, h2f_hw(h));
        S[(size_t)row * LDA + col] = h;
      }
    }
  }
  red[tid] = lmin;
  __syncthreads();
  for (int sN = 128; sN >= 1; sN >>= 1) {
    if (tid < sN) red[tid] = fminf(red[tid], red[tid + sN]);
    __syncthreads();
  }
  if (tid == 0) gmin[blockIdx.y * 32 + blockIdx.x] = red[0];
}

/* ------- sims_no -> S col NN + loss_op partial ------- */
__global__ void colvec_kernel(const u16* img, const u16* txt, const u16* tno,
                              u16* S, float* colvals, float* opP, const float* misc) {
  __shared__ float shOp[4];
  const int isF = ((const int*)misc)[10];
  const int wv = threadIdx.x >> 6;
  const int row = (int)(blockIdx.x << 2) + wv;
  const int lane = threadIdx.x & 63;
  const size_t base = (size_t)row * DD + lane * 8;
  float xi[8], xt[8], xn[8];
  if (isF) {
    const float* fi = (const float*)img;
    const float* ft = (const float*)txt;
    const float* fn = (const float*)tno;
    #pragma unroll
    for (int c = 0; c < 8; ++c) { xi[c] = fi[base+c]; xt[c] = ft[base+c]; xn[c] = fn[base+c]; }
  } else {
    Q qi = *(const Q*)(img + base);
    Q qt = *(const Q*)(txt + base);
    Q qn = *(const Q*)(tno + base);
    xi[0]=bflo(qi.x); xi[1]=bfhi(qi.x); xi[2]=bflo(qi.y); xi[3]=bfhi(qi.y);
    xi[4]=bflo(qi.z); xi[5]=bfhi(qi.z); xi[6]=bflo(qi.w); xi[7]=bfhi(qi.w);
    xt[0]=bflo(qt.x); xt[1]=bfhi(qt.x); xt[2]=bflo(qt.y); xt[3]=bfhi(qt.y);
    xt[4]=bflo(qt.z); xt[5]=bfhi(qt.z); xt[6]=bflo(qt.w); xt[7]=bfhi(qt.w);
    xn[0]=bflo(qn.x); xn[1]=bfhi(qn.x); xn[2]=bflo(qn.y); xn[3]=bfhi(qn.y);
    xn[4]=bflo(qn.z); xn[5]=bfhi(qn.z); xn[6]=bflo(qn.w); xn[7]=bfhi(qn.w);
  }
  float sn = 0.f, cs = 0.f;
  #pragma unroll
  for (int c = 0; c < 8; ++c) { sn += xi[c]*xn[c]; cs += xt[c]*xn[c]; }
  #pragma unroll
  for (int off = 32; off >= 1; off >>= 1) { sn += __shfl_xor(sn, off); cs += __shfl_xor(cs, off); }
  if (lane == 0) {
    colvals[row] = sn;
    S[(size_t)row * LDA + NN] = f2h_hw(sn);
    shOp[wv] = fmaxf(cs + 0.2f, 0.f) + fmaxf(-0.7f - cs, 0.f);
  }
  __syncthreads();
  if (threadIdx.x == 0) opP[blockIdx.x] = shOp[0] + shOp[1] + shOp[2] + shOp[3];
}

__global__ void reduce_kernel(const float* gmin, const float* colvals,
                              const float* opP, float* misc) {
  __shared__ float smin[256];
  __shared__ float ssum[256];
  float mn = 1e30f, sm = 0.f;
  for (int i = threadIdx.x; i < 1024; i += 256) mn = fminf(mn, gmin[i]);
  for (int i = threadIdx.x; i < 4096; i += 256) mn = fminf(mn, h2f_hw(f2h_hw(colvals[i])));
  for (int i = threadIdx.x; i < 1024; i += 256) sm += opP[i];
  smin[threadIdx.x] = mn; ssum[threadIdx.x] = sm;
  __syncthreads();
  for (int sN = 128; sN >= 1; sN >>= 1) {
    if (threadIdx.x < sN) {
      smin[threadIdx.x] = fminf(smin[threadIdx.x], smin[threadIdx.x + sN]);
      ssum[threadIdx.x] += ssum[threadIdx.x + sN];
    }
    __syncthreads();
  }
  if (threadIdx.x == 0) {
    float maxC = 1.0f - smin[0];         /* max(1-S) = 1 - min(S) */
    float a = 1.0f / (maxC * REGc);
    misc[1] = a;
    misc[4] = ssum[0];
    misc[5] = __expf(-a);                /* ea */
    misc[6] = a * 1.4426950408889634f;   /* b = a*log2(e) for exp2 fast path */
  }
}

__global__ void preds_kernel(const u16* S, const float* misc, float* preds) {
  const int row = (int)(blockIdx.x << 2) + (int)(threadIdx.x >> 6);
  const int lane = threadIdx.x & 63;
  const float scale = misc[0];
  const u16* Sr = S + (size_t)row * LDA;
  float m = NEGINF, s = 0.f;
  for (int it = 0; it < 8; ++it) {
    const int j0 = (it << 9) + (lane << 3);
    float x[8];
    unpack8(*(const Q*)(Sr + j0), x);
    float lm = NEGINF;
    #pragma unroll
    for (int c = 0; c < 8; ++c) { x[c] *= scale; lm = fmaxf(lm, x[c]); }
    float lsum = 0.f;
    #pragma unroll
    for (int c = 0; c < 8; ++c) lsum += __expf(x[c] - lm);
    lse_merge(m, s, lm, lsum);
  }
  #pragma unroll
  for (int off = 32; off >= 1; off >>= 1) {
    float om = __shfl_xor(m, off), os = __shfl_xor(s, off);
    lse_merge(m, s, om, os);
  }
  if (lane == 0) {
    float sii = h2f_hw(Sr[row]);
    preds[row] = __expf(scale * sii - m) / s;
  }
}

/* ------- nc rank: one block per row ------- */
__global__ void rank_kernel(const float* preds, int* is_nc) {
  const int i = blockIdx.x;
  const float pv = preds[i];
  float cnt = 0.f;
  for (int k2 = threadIdx.x; k2 < NN; k2 += 256) {
    float pk = preds[k2];
    cnt += (pk < pv || (pk == pv && k2 < i)) ? 1.f : 0.f;
  }
  cnt = blockReduce256(cnt);
  if (threadIdx.x == 0) is_nc[i] = (cnt < (float)NCNUM) ? 1 : 0;
}

__device__ __forceinline__ bool unmasked(int j, int r, bool ncr) {
  return (j == NN) ? ncr : !((j == r) && ncr);
}

/* ------- fence-free monotonic tree barrier (round-24 proven design) ------- */
__device__ __forceinline__ void gridbar(int* bar, int bid, int phase, bool& dead) {
  __syncthreads();
  if (threadIdx.x == 0 && !dead) {
    const int g = bid & 31;
    if (__hip_atomic_fetch_add(&bar[g << 4], 1, __ATOMIC_RELAXED,
                               __HIP_MEMORY_SCOPE_AGENT) == 32 * phase - 1) {
      if (__hip_atomic_fetch_add(&bar[32 << 4], 1, __ATOMIC_RELAXED,
                                 __HIP_MEMORY_SCOPE_AGENT) == 32 * phase - 1) {
        #pragma unroll
        for (int gg = 0; gg < 32; ++gg)
          __hip_atomic_store(&bar[(gg << 4) + 8], phase, __ATOMIC_RELAXED,
                             __HIP_MEMORY_SCOPE_AGENT);
      }
    }
    int spins = 0;
    while (__hip_atomic_load(&bar[(g << 4) + 8], __ATOMIC_RELAXED,
                             __HIP_MEMORY_SCOPE_AGENT) < phase) {
      __builtin_amdgcn_s_sleep(2);
      if (++spins > (1 << 21)) { dead = true; break; }   /* ~0.1s sticky cap */
    }
  }
  __syncthreads();
}

/* ------- one sinkhorn sub-step with cached E; prev sums preloaded ---- */
template<int RB, int FIN>
__device__ __forceinline__ void substep(
    float (&Ec)[8][8], int k,
    int c1, int c2, int c1p, int c2p,
    float pr, float prN,
    float* outRow, float* outCol,
    float* z1, float* z2, int nz1, int nz2,
    float* errs1, float* errs2,
    float* uvec, float* utvec, float* vvec, float* vtvec,
    float* shW1, float* shW2, float (*shAcc)[128], float* sh4096,
    float* se,
    float ea, int rt, int ct, int bid, int tid, int tc, int tr,
    int j0c, int r0, int cbase, bool isLast) {

  const int gRow = RB ? c2 : c1;
  const int gCol = RB ? c1 : c2;

  if (!FIN) {
    const int z = bid * 256 + tid;          /* 8200 < 262144: one shot */
    if (z < nz1) stu(&z1[z], 0.f);
    else if (z - nz1 < nz2) stu(&z2[z - nz1], 0.f);
  }

  float errd = 0.f;
  if (tid < 128) {
    const int i = r0 + tid;
    float w = 0.f;
    if (!RB) {
      if (!FIN && !gCol) w = (k == 0) ? ea : ea / (4096.0f * pr);
      if (ct == 0 && k >= 1 && !c2p) stu(&vtvec[i], REGc * (-LOGN - __logf(pr)));
    } else {
      if (!gCol) {
        w = ea / (4096.0f * pr);
        if (ct == 0) {
          float un = REGc * (-LOGN - __logf(pr));
          errd = fabsf(un - uvec[i]);
          uvec[i] = un;
        }
      }
    }
    shW2[tid] = w;
  } else {
    const int j = cbase + (tid - 128);
    float w = 0.f;
    if (!RB) {
      if (!FIN && !gRow) w = (k == 0) ? ea : ea / (4097.0f * pr);
      if (rt == 0 && k >= 1 && !c1p) stu(&vvec[j], REGc * (-LOGM - __logf(pr)));
    } else {
      if (!gRow) {
        w = ea / (4097.0f * pr);
        if (rt == 0) {
          float un = REGc * (-LOGM - __logf(pr));
          errd = fabsf(un - utvec[j]);
          utvec[j] = un;
        }
      }
    }
    shW1[tid - 128] = w;
    if (isLast && tid == 128) {        /* col 4096 sidecar weight */
      float w2 = 0.f;
      if (!RB) {
        if (!FIN && !gRow) w2 = (k == 0) ? ea : ea / (4097.0f * prN);
        if (rt == 0 && k >= 1 && !c1p) stu(&vvec[NN], REGc * (-LOGM - __logf(prN)));
      } else {
        if (!gRow) {
          w2 = ea / (4097.0f * prN);
          if (rt == 0) {
            float un = REGc * (-LOGM - __logf(prN));
            errd += fabsf(un - utvec[NN]);
            utvec[NN] = un;
          }
        }
      }
      shW1[128] = w2;
    }
  }
  __syncthreads();

  if (!FIN && !(gRow && gCol)) {
    float W1l[8];
    #pragma unroll
    for (int c = 0; c < 8; ++c) W1l[c] = shW1[j0c + c];
    float cs[8];
    #pragma unroll
    for (int c = 0; c < 8; ++c) cs[c] = 0.f;
    const float w4096 = isLast ? shW1[128] : 0.f;
    #pragma unroll
    for (int st = 0; st < 8; ++st) {
      const int rr = (st << 4) + tr;
      if (!gCol) {
        const float Wr = shW2[rr];
        #pragma unroll
        for (int c = 0; c < 8; ++c) cs[c] = fmaf(Ec[st][c], Wr, cs[c]);
      }
      if (!gRow) {
        float rs = 0.f;
        #pragma unroll
        for (int c = 0; c < 8; ++c) rs = fmaf(Ec[st][c], W1l[c], rs);
        #pragma unroll
        for (int off = 8; off >= 1; off >>= 1) rs += __shfl_xor(rs, off);
        if (tc == 0) {
          if (isLast) rs += sh4096[rr] * w4096;
          atomicAdd(&outRow[r0 + rr], rs);
        }
      }
    }
    if (!gCol) {
      #pragma unroll
      for (int c = 0; c < 8; ++c) shAcc[tr][j0c + c] = cs[c];
      __syncthreads();
      if (tid < 128) {
        float s2 = 0.f;
        #pragma unroll
        for (int g = 0; g < 16; ++g) s2 += shAcc[g][tid];
        atomicAdd(&outCol[cbase + tid], s2);
      }
      if (isLast && tid >= 128 && tid < 192) {   /* colsum for j=4096 */
        const int l = tid - 128;
        float s3 = sh4096[l] * shW2[l] + sh4096[l + 64] * shW2[l + 64];
        #pragma unroll
        for (int off = 32; off >= 1; off >>= 1) s3 += __shfl_xor(s3, off);
        if (l == 0) atomicAdd(&outCol[NN], s3);
      }
    }
  }

  if (RB) {
    float e2 = errd;
    #pragma unroll
    for (int off = 32; off >= 1; off >>= 1) e2 += __shfl_xor(e2, off);
    if ((tid & 63) == 0) se[tid >> 6] = e2;
    __syncthreads();
    if (tid == 0) {
      if (ct == 0) atomicAdd(&errs1[k], se[0] + se[1]);
      if (rt == 0) atomicAdd(&errs2[k], se[2] + se[3]);
    }
  }
}

/* ------- persistent sinkhorn + fused final/combine/loss/finish ------- */
__global__ __launch_bounds__(256, 4) void sink_persist(
    const u16* S, const float* misc, float* errs1, float* errs2,
    float* uvec, float* utvec, float* vvec, float* vtvec,
    float* rsA0, float* rsA1, float* csA0, float* csA1,
    float* rsB0, float* rsB1, float* csB0, float* csB1,
    const int* is_nc, int* bar,
    float* rowLm, float* rowLs, float* rowGs,
    float* colLm, float* colLs, float* colGs,
    float* LSMrow, float* LBLm, float* LBLs,
    float* LSMcol, float* LBTm, float* LBTs,
    float* imgP, float* txtP, float* out) {
  __shared__ float shW1[129];
  __shared__ float shW2[128];
  __shared__ float shAcc[16][128];
  __shared__ float sh4096[128];
  __shared__ int   shG[4];
  __shared__ float se[4];
  __shared__ float shm[16][128];
  __shared__ float shs[16][128];

  const int tid = threadIdx.x;
  const int rt = blockIdx.x, ct = blockIdx.y;
  const int bid = ct * 32 + rt;
  const int cbase = ct << 7, r0 = rt << 7;
  const float a = misc[1], ea = misc[5], b = misc[6];
  const int tc = tid & 15, tr = tid >> 4;
  const int j0c = tc << 3;
  const bool isLast = (ct == 31);

  /* ---- build E tile in registers, masks baked in ---- */
  float Ec[8][8];
  if (rt != ct) {
    #pragma unroll
    for (int st = 0; st < 8; ++st) {
      const int rr = (st << 4) + tr;
      H8 hh; hh.q = *(const Q*)(S + (size_t)(r0 + rr) * LDA + cbase + j0c);
      #pragma unroll
      for (int c = 0; c < 8; ++c) Ec[st][c] = exp2_fast((float)hh.h[c] * b);
    }
  } else {
    #pragma unroll
    for (int st = 0; st < 8; ++st) {
      const int rr = (st << 4) + tr;
      const int r = r0 + rr;
      float xv[8];
      unpack8(*(const Q*)(S + (size_t)r * LDA + cbase + j0c), xv);
      const bool ncr = (is_nc[r] != 0);
      #pragma unroll
      for (int c = 0; c < 8; ++c) {
        float e = __expf(xv[c] * a);
        if ((j0c + c == rr) && ncr) e = 0.f;   /* diag mask (cbase==r0) */
        Ec[st][c] = e;
      }
    }
  }
  if (isLast && tid < 128) {
    const int r = r0 + tid;
    float x = h2f_hw(S[(size_t)r * LDA + NN]);
    sh4096[tid] = (is_nc[r] != 0) ? __expf(x * a) : 0.f;
  }
  __syncthreads();

  bool dead = false;
  int phase = 0;
  for (int k = 0; k < 100; ++k) {
    const int p = k & 1;
    const int q2 = 1 - p;
    const int pm = (k > 0) ? q2 : 0;
    /* prev loads for substep A + gate loads: issued CONCURRENTLY */
    const float* pRowA = pm ? rsB1 : rsB0;
    const float* pColA = pm ? csB1 : csB0;
    float prA = 0.f, prAN = 0.f;
    if (tid < 128) {
      prA = ldu(&pRowA[r0 + tid]);
    } else {
      prA = ldu(&pColA[cbase + (tid - 128)]);
      if (isLast && tid == 128) prAN = ldu(&pColA[NN]);
    }
    if (tid < 4) {
      const int kk = k - 1 - (tid >> 1);
      const float* ep = (tid & 1) ? errs2 : errs1;
      shG[tid] = (kk >= 0) && (ldu(&ep[kk]) < THRESHc);
    }
    __syncthreads();
    const int c1 = shG[0], c2 = shG[1], c1p = shG[2], c2p = shG[3];
    if (c1 && c2 && c1p && c2p) break;   /* remaining substeps provably no-op */

    substep<0, 0>(Ec, k, c1, c2, c1p, c2p, prA, prAN,
        p ? rsA1 : rsA0, p ? csA1 : csA0,
        p ? csB1 : csB0, p ? rsB1 : rsB0, 4104, 4096,
        errs1, errs2, uvec, utvec, vvec, vtvec,
        shW1, shW2, shAcc, sh4096, se,
        ea, rt, ct, bid, tid, tc, tr, j0c, r0, cbase, isLast);
    gridbar(bar, bid, ++phase, dead);

    const float* pRowB = p ? rsA1 : rsA0;
    const float* pColB = p ? csA1 : csA0;
    float prB = 0.f, prBN = 0.f;
    if (tid < 128) {
      prB = ldu(&pRowB[r0 + tid]);
    } else {
      prB = ldu(&pColB[cbase + (tid - 128)]);
      if (isLast && tid == 128) prBN = ldu(&pColB[NN]);
    }
    substep<1, 0>(Ec, k, c1, c2, c1p, c2p, prB, prBN,
        p ? rsB1 : rsB0, p ? csB1 : csB0,
        q2 ? rsA1 : rsA0, q2 ? csA1 : csA0, 4096, 4104,
        errs1, errs2, uvec, utvec, vvec, vtvec,
        shW1, shW2, shAcc, sh4096, se,
        ea, rt, ct, bid, tid, tc, tr, j0c, r0, cbase, isLast);
    gridbar(bar, bid, ++phase, dead);
  }

  /* final weight-only step (k=100); gates for k=100 (all-true if broken) */
  {
    float prF = 0.f, prFN = 0.f;
    if (tid < 128) {
      prF = ldu(&rsB1[r0 + tid]);
    } else {
      prF = ldu(&csB1[cbase + (tid - 128)]);
      if (isLast && tid == 128) prFN = ldu(&csB1[NN]);
    }
    if (tid < 4) {
      const int kk = 99 - (tid >> 1);
      const float* ep = (tid & 1) ? errs2 : errs1;
      shG[tid] = (ldu(&ep[kk]) < THRESHc);
    }
    __syncthreads();
    substep<0, 1>(Ec, 100, shG[0], shG[1], shG[2], shG[3], prF, prFN,
        rsA0, csA0, rsA0, csA0, 0, 0,
        errs1, errs2, uvec, utvec, vvec, vtvec,
        shW1, shW2, shAcc, sh4096, se,
        ea, rt, ct, bid, tid, tc, tr, j0c, r0, cbase, isLast);
  }

  /* ======== fused tail ======== */
  gridbar(bar, bid, ++phase, dead);
  const float scale = misc[0];

  /* ---- stage F: final_pass for tile (rt, ct); all j < NN here ---- */
  {
    float wc[8];
    #pragma unroll
    for (int c = 0; c < 8; ++c) wc[c] = ldu(&vvec[cbase + j0c + c]) * INVREG;
    float cLm[8], cLs[8], cGs[8];
    #pragma unroll
    for (int c = 0; c < 8; ++c) { cLm[c] = NEGINF; cLs[c] = 0.f; cGs[c] = 0.f; }
    for (int st = 0; st < 8; ++st) {
      const int r = r0 + (st << 4) + tr;
      float xv[8], lg[8]; unsigned um = 0;
      float raw[8];
      unpack8(*(const Q*)(S + (size_t)r * LDA + cbase + j0c), raw);
      const bool ncr = (is_nc[r] != 0);
      const float vtr = ldu(&vtvec[r]) * INVREG;
      #pragma unroll
      for (int c = 0; c < 8; ++c) {
        xv[c] = raw[c] * a;
        lg[c] = scale * raw[c];
        cGs[c] += __expf(lg[c]);
        if (!((cbase + j0c + c == r) && ncr)) {
          um |= 1u << c;
          float e2 = xv[c] + vtr;
          float nm = fmaxf(cLm[c], e2);
          cLs[c] = cLs[c] * __expf(cLm[c] - nm) + __expf(e2 - nm);
          cLm[c] = nm;
        }
      }
      float rsG = 0.f;
      #pragma unroll
      for (int c = 0; c < 8; ++c) rsG += __expf(lg[c]);
      #pragma unroll
      for (int off = 8; off >= 1; off >>= 1) rsG += __shfl_xor(rsG, off);
      float rmL = NEGINF;
      #pragma unroll
      for (int c = 0; c < 8; ++c) if (um >> c & 1u) rmL = fmaxf(rmL, xv[c] + wc[c]);
      #pragma unroll
      for (int off = 8; off >= 1; off >>= 1) rmL = fmaxf(rmL, __shfl_xor(rmL, off));
      float rsL = 0.f;
      if (rmL > NEGINF) {
        #pragma unroll
        for (int c = 0; c < 8; ++c) if (um >> c & 1u) rsL += __expf(xv[c] + wc[c] - rmL);
      }
      #pragma unroll
      for (int off = 8; off >= 1; off >>= 1) rsL += __shfl_xor(rsL, off);
      if (tc == 0) {
        stu(&rowGs[ct * NN + r], rsG);
        stu(&rowLm[ct * NN + r], rmL);
        stu(&rowLs[ct * NN + r], rsL);
      }
    }
    #pragma unroll
    for (int c = 0; c < 8; ++c) { shm[tr][j0c + c] = cLm[c]; shs[tr][j0c + c] = cLs[c]; }
    __syncthreads();
    if (tid < 128) {
      float m = NEGINF, s = 0.f;
      #pragma unroll
      for (int g = 0; g < 16; ++g) lse_merge(m, s, shm[g][tid], shs[g][tid]);
      stu(&colLm[rt * LDA + cbase + tid], m);
      stu(&colLs[rt * LDA + cbase + tid], s);
    }
    __syncthreads();
    #pragma unroll
    for (int c = 0; c < 8; ++c) shs[tr][j0c + c] = cGs[c];
    __syncthreads();
    if (tid < 128) {
      float s = 0.f;
      #pragma unroll
      for (int g = 0; g < 16; ++g) s += shs[g][tid];
      stu(&colGs[rt * LDA + cbase + tid], s);
    }
    /* sidecar: pseudo-tile ct=32 (the j==4096 column), same thread pattern
       as the standalone ct==32 block -> bit-exact partials */
    if (isLast) {
      __syncthreads();
      if (tid < 128) {
        const int r = r0 + tid;
        float rawN = h2f_hw(S[(size_t)r * LDA + NN]);
        int ncrN = is_nc[r];
        float rsG = __expf(scale * rawN);
        float xvN = rawN * a;
        float wcN = ldu(&vvec[NN]) * INVREG;
        float rmL = ncrN ? (xvN + wcN) : NEGINF;
        float rsL = ncrN ? 1.f : 0.f;      /* exp(0) == 1 exact */
        stu(&rowGs[32 * NN + r], rsG);
        stu(&rowLm[32 * NN + r], rmL);
        stu(&rowLs[32 * NN + r], rsL);
      }
      float cLmN = NEGINF, cLsN = 0.f, cGsN = 0.f;
      if (tc == 0) {
        #pragma unroll
        for (int st = 0; st < 8; ++st) {
          const int r = r0 + (st << 4) + tr;
          float rw = h2f_hw(S[(size_t)r * LDA + NN]);
          float xvN = rw * a;
          cGsN += __expf(scale * rw);
          if (is_nc[r]) {
            float vtr = ldu(&vtvec[r]) * INVREG;
            float e2 = xvN + vtr;
            float nm = fmaxf(cLmN, e2);
            cLsN = cLsN * __expf(cLmN - nm) + __expf(e2 - nm);
            cLmN = nm;
          }
        }
      }
      __syncthreads();
      if (tc == 0) { shm[tr][0] = cLmN; shs[tr][0] = cLsN; shAcc[tr][0] = cGsN; }
      __syncthreads();
      if (tid == 0) {
        float m = NEGINF, s = 0.f, sg = 0.f;
        for (int g = 0; g < 16; ++g) {
          lse_merge(m, s, shm[g][0], shs[g][0]);
          sg += shAcc[g][0];
        }
        stu(&colLm[rt * LDA + NN], m);
        stu(&colLs[rt * LDA + NN], s);
        stu(&colGs[rt * LDA + NN], sg);
      }
    }
  }
  gridbar(bar, bid, ++phase, dead);

  /* ---- stage C: combine, 8193 outputs, 1 thread each, serial order ---- */
  {
    int o = bid * 8 + tid;
    bool act = (tid < 8);
    if (bid == 1023 && tid == 8) { act = true; o = 8192; }
    if (act) {
      if (o < 4096) {
        const int i = o;
        float m = NEGINF, s = 0.f, sg = 0.f;
        for (int t = 0; t < 33; ++t) {
          lse_merge(m, s, ldu(&rowLm[t * NN + i]), ldu(&rowLs[t * NN + i]));
          sg += ldu(&rowGs[t * NN + i]);
        }
        stu(&LBLm[i], m); stu(&LBLs[i], s);
        stu(&LSMrow[i], __logf(sg));
      } else {
        const int j = o - 4096;
        float m = NEGINF, s = 0.f, sg = 0.f;
        for (int t = 0; t < 32; ++t) {
          lse_merge(m, s, ldu(&colLm[t * LDA + j]), ldu(&colLs[t * LDA + j]));
          sg += ldu(&colGs[t * LDA + j]);
        }
        stu(&LBTm[j], m); stu(&LBTs[j], s);
        stu(&LSMcol[j], __logf(sg));
      }
    }
  }
  gridbar(bar, bid, ++phase, dead);

  /* ---- stage L: loss_pass for tile (rt, ct) + sidecar ---- */
  {
    float vcw[8], bm[8], bsi[8], cg[8];
    #pragma unroll
    for (int c = 0; c < 8; ++c) {
      const int j = cbase + j0c + c;
      vcw[c] = ldu(&vvec[j]) * INVREG;
      bm[c] = ldu(&LBTm[j]);
      bsi[c] = 1.f / ldu(&LBTs[j]);
      cg[c] = ldu(&LSMcol[j]);
    }
    float sImg = 0.f, sTxt = 0.f;
    for (int st = 0; st < 8; ++st) {
      const int r = r0 + (st << 4) + tr;
      float raw[8];
      unpack8(*(const Q*)(S + (size_t)r * LDA + cbase + j0c), raw);
      const bool ncr = (is_nc[r] != 0);
      const float vtr = ldu(&vtvec[r]) * INVREG;
      const float rm = ldu(&LBLm[r]), rsi = 1.f / ldu(&LBLs[r]), rg = ldu(&LSMrow[r]);
      #pragma unroll
      for (int c = 0; c < 8; ++c) {
        const int j = cbase + j0c + c;
        float xv = raw[c] * a;
        float lgt = scale * raw[c];
        bool unm = !((j == r) && ncr);
        bool lv = (j == r) && !ncr;
        float rr2 = unm ? __expf(xv + vcw[c] - rm) * rsi : 0.f;
        float t = GAM * rr2 + (lv ? 0.2f : 0.f);
        if (t > 0.f) sImg += t * (__logf(t) - (lgt - rg));
        float r2 = unm ? __expf(xv + vtr - bm[c]) * bsi[c] : 0.f;
        float t2 = GAM * r2 + (lv ? 0.2f : 0.f);
        if (t2 > 0.f) sTxt += t2 * (__logf(t2) - (lgt - cg[c]));
      }
    }
    sImg = blockReduce256(sImg);
    sTxt = blockReduce256(sTxt);
    if (tid == 0) {
      stu(&imgP[rt * 33 + ct], sImg);
      stu(&txtP[rt * 33 + ct], sTxt);
    }
    if (isLast) {
      float sI = 0.f, sT = 0.f;
      if (tc == 0) {
        const float vcwN = ldu(&vvec[NN]) * INVREG;
        const float bmN = ldu(&LBTm[NN]);
        const float bsiN = 1.f / ldu(&LBTs[NN]);
        const float cgN = ldu(&LSMcol[NN]);
        #pragma unroll
        for (int st = 0; st < 8; ++st) {
          const int r = r0 + (st << 4) + tr;
          float rw = h2f_hw(S[(size_t)r * LDA + NN]);
          const bool ncr = (is_nc[r] != 0);
          float xv = rw * a;
          float lgt = scale * rw;
          const float vtr = ldu(&vtvec[r]) * INVREG;
          const float rm = ldu(&LBLm[r]), rsi = 1.f / ldu(&LBLs[r]), rg = ldu(&LSMrow[r]);
          float rr2 = ncr ? __expf(xv + vcwN - rm) * rsi : 0.f;
          float t = GAM * rr2 + (ncr ? 0.2f : 0.f);
          if (t > 0.f) sI += t * (__logf(t) - (lgt - rg));
          float r2 = ncr ? __expf(xv + vtr - bmN) * bsiN : 0.f;
          float t2 = GAM * r2 + (ncr ? 0.2f : 0.f);
          if (t2 > 0.f) sT += t2 * (__logf(t2) - (lgt - cgN));
        }
      }
      sI = blockReduce256(sI);
      sT = blockReduce256(sT);
      if (tid == 0) {
        stu(&imgP[rt * 33 + 32], sI);
        stu(&txtP[rt * 33 + 32], sT);
      }
    }
  }
  gridbar(bar, bid, ++phase, dead);

  /* ---- stage E: finish (block 0, serial order identical to standalone) */
  if (bid == 0) {
    float vi = 0.f, vtx = 0.f;
    for (int idx = tid; idx < 1056; idx += 256) {
      vi += ldu(&imgP[idx]);
      vtx += ldu(&txtP[idx]);
    }
    vi = blockReduce256(vi);
    vtx = blockReduce256(vtx);
    if (tid == 0) {
      float loss_img = vi / 4096.0f;
      float loss_txt = vtx / 4097.0f;
      float loss_ul = 0.5f * (loss_img + loss_txt);
      float loss_op = misc[4] / 4096.0f;
      if (vi == 0.f && vtx == 0.f) loss_ul = 777.0f;
      if (!(loss_ul == loss_ul))   loss_ul = 888.0f;
      out[0] = loss_ul;
      out[1] = loss_op;
    }
  }
}

extern "C" void kernel_launch(void* const* d_in, const int* in_sizes, int n_in,
                              void* d_out, int out_size, void* d_ws, size_t ws_size,
                              hipStream_t stream) {
  (void)in_sizes; (void)n_in; (void)out_size;
  const u16* img = (const u16*)d_in[0];
  const u16* txt = (const u16*)d_in[1];
  const u16* tno = (const u16*)d_in[2];
  const u16* ls  = (const u16*)d_in[3];
  float* out = (float*)d_out;

  ContrastiveLoss_83391085019222_kernel<<<1, 64, 0, stream>>>(out);

  size_t off = 0;
  char* w = (char*)d_ws;
  u16* S; u16* Abf; u16* Bbf;
  float *rsA0, *rsA1, *csA0, *csA1, *rsB0, *rsB1, *csB0, *csB1, *errs;
  float *rowLm, *rowLs, *rowGs, *colLm, *colLs, *colGs;
  float *vecs, *preds, *colvals, *gmin, *opP;
  float *LSMrow, *LBLm, *LBLs, *LSMcol, *LBTm, *LBTs, *imgP, *txtP, *misc;
  int* is_nc; int* bar;
  #define ALLOC(ptr, type, nbytes) ptr = (type)(w + off); off = (off + (size_t)(nbytes) + 255) & ~(size_t)255
  ALLOC(S,      u16*,   (size_t)NN * LDA * 2);
  ALLOC(Abf,    u16*,   (size_t)NN * DD * 2);
  ALLOC(Bbf,    u16*,   (size_t)NN * DD * 2);
  ALLOC(rsA0,   float*, 4096 * 4);
  ALLOC(rsA1,   float*, 4096 * 4);
  ALLOC(csA0,   float*, 4104 * 4);
  ALLOC(csA1,   float*, 4104 * 4);
  ALLOC(rsB0,   float*, 4096 * 4);
  ALLOC(rsB1,   float*, 4096 * 4);
  ALLOC(csB0,   float*, 4104 * 4);
  ALLOC(csB1,   float*, 4104 * 4);
  ALLOC(errs,   float*, 256 * 4);
  ALLOC(rowLm,  float*, (size_t)33 * NN * 4);
  ALLOC(rowLs,  float*, (size_t)33 * NN * 4);
  ALLOC(rowGs,  float*, (size_t)33 * NN * 4);
  ALLOC(colLm,  float*, (size_t)32 * LDA * 4);
  ALLOC(colLs,  float*, (size_t)32 * LDA * 4);
  ALLOC(colGs,  float*, (size_t)32 * LDA * 4);
  ALLOC(vecs,   float*, 16400 * 4);
  ALLOC(preds,  float*, NN * 4);
  ALLOC(is_nc,  int*,   NN * 4);
  ALLOC(colvals,float*, NN * 4);
  ALLOC(gmin,   float*, 1024 * 4);
  ALLOC(opP,    float*, 1024 * 4);
  ALLOC(LSMrow, float*, NN * 4);
  ALLOC(LBLm,   float*, NN * 4);
  ALLOC(LBLs,   float*, NN * 4);
  ALLOC(LSMcol, float*, LDA * 4);
  ALLOC(LBTm,   float*, LDA * 4);
  ALLOC(LBTs,   float*, LDA * 4);
  ALLOC(imgP,   float*, 1056 * 4);
  ALLOC(txtP,   float*, 1056 * 4);
  ALLOC(bar,    int*,   4096);
  ALLOC(misc,   float*, 64);
  #undef ALLOC

  if (ws_size < off) {
    diag_kernel<<<1, 64, 0, stream>>>(out, -(float)(ws_size / 1000000.0),
                                      -(float)(off / 1000000.0));
    return;
  }

  float* uvec  = vecs;
  float* vvec  = vecs + 4096;
  float* utvec = vecs + 8200;
  float* vtvec = vecs + 12304;
  float* errs1 = errs;
  float* errs2 = errs + 128;

  detect_kernel<<<1, 64, 0, stream>>>(img, misc);
  cvt_kernel<<<2048, 256, 0, stream>>>(img, txt, Abf, Bbf, misc);
  init_kernel<<<65, 256, 0, stream>>>(ls, vecs, errs, rsA0, csA0, bar, misc);
  gemm_mfma<<<dim3(32, 32), 256, 0, stream>>>(Abf, Bbf, S, gmin);
  colvec_kernel<<<1024, 256, 0, stream>>>(img, txt, tno, S, colvals, opP, misc);
  reduce_kernel<<<1, 256, 0, stream>>>(gmin, colvals, opP, misc);

  preds_kernel<<<1024, 256, 0, stream>>>(S, misc, preds);
  rank_kernel<<<4096, 256, 0, stream>>>(preds, is_nc);

  /* persistent sinkhorn + fused tail: 1024 blocks, 4/CU by launch bounds */
  sink_persist<<<dim3(32, 32), 256, 0, stream>>>(S, misc, errs1, errs2,
      uvec, utvec, vvec, vtvec,
      rsA0, rsA1, csA0, csA1, rsB0, rsB1, csB0, csB1,
      is_nc, bar,
      rowLm, rowLs, rowGs, colLm, colLs, colGs,
      LSMrow, LBLm, LBLs, LSMcol, LBTm, LBTs,
      imgP, txtP, out);
}

// Round 9
// 325.952 us; speedup vs baseline: 1.2656x; 1.0453x over previous
//

#include <hip/hip_runtime.h>
#include <hip/hip_bf16.h>

// ROUND 29 (round 28: 340.7 us, absmax 0.0; fusion landed but tail costs
// ~107 us inside sink_persist: ~16.7M redundant agent-scope ldu loads of
// per-row/col vectors (x16 per value, serialized at LLC)):
//  - tail stages now COOPERATIVELY STAGE each needed 128-vector into LDS
//    once per block via coalesced PLAIN loads (safe: vectors are stu-written
//    strictly before a gridbar and never plain-touched earlier -> first
//    plain read misses L2 and fetches the fresh LLC copy). Stage F: 2
//    vectors; stage L: 8 vectors; stages C/E: plain loads directly.
//  - arithmetic order unchanged -> bit-exact. Everything else identical
//    to round 28.

#define NN 4096
#define LDA 4104          /* fp16 row stride for S (4097 padded to x8) */
#define DD 512
#define NCNUM 409         /* int(0.1*4096) */
#define REGc 0.03f
#define INVREG (1.0f/0.03f)
#define GAM 0.8f
#define THRESHc 1e-4f
#define LOGN 8.3177661667193433f   /* ln(4096) */
#define LOGM 8.3180102775477533f   /* ln(4097) */
#define NEGINF (-__builtin_inff())

typedef unsigned short u16;
typedef unsigned int u32;
typedef _Float16 f16;

struct alignas(16) Q  { u32 x, y, z, w; };
union H8 { Q q; f16 h[8]; };

typedef __attribute__((ext_vector_type(8))) short frag_ab;   /* 8 bf16 */
typedef __attribute__((ext_vector_type(4))) float frag_cd;   /* 4 f32  */

__device__ __forceinline__ float bf2f(u32 u) { return __uint_as_float(u << 16); }
__device__ __forceinline__ float bflo(u32 w) { return __uint_as_float(w << 16); }
__device__ __forceinline__ float bfhi(u32 w) { return __uint_as_float(w & 0xFFFF0000u); }
__device__ __forceinline__ u16 f2bf_rne(float f) {
  u32 b = __float_as_uint(f);
  b += 0x7FFFu + ((b >> 16) & 1u);
  return (u16)(b >> 16);
}
__device__ __forceinline__ u16 f2h_hw(float f) {
  union { f16 h; u16 u; } X; X.h = (f16)f; return X.u;
}
__device__ __forceinline__ float h2f_hw(u16 v) {
  union { u16 u; f16 h; } X; X.u = v; return (float)X.h;
}
__device__ __forceinline__ float exp2_fast(float x) {
#if __has_builtin(__builtin_amdgcn_exp2f)
  return __builtin_amdgcn_exp2f(x);
#else
  float r; asm("v_exp_f32 %0, %1" : "=v"(r) : "v"(x)); return r;
#endif
}
/* LLC-point (agent-scope, relaxed) load/store: no L2 invalidate/writeback */
__device__ __forceinline__ float ldu(const float* p) {
  return __hip_atomic_load(p, __ATOMIC_RELAXED, __HIP_MEMORY_SCOPE_AGENT);
}
__device__ __forceinline__ void stu(float* p, float v) {
  __hip_atomic_store(p, v, __ATOMIC_RELAXED, __HIP_MEMORY_SCOPE_AGENT);
}
/* async global->LDS, 16B per lane; lds base must be wave-uniform */
__device__ __forceinline__ void gload_lds16(const u16* g, u16* l) {
  __builtin_amdgcn_global_load_lds(
      (const __attribute__((address_space(1))) u32*)g,
      (__attribute__((address_space(3))) u32*)l, 16, 0, 0);
}
__device__ __forceinline__ void unpack8(Q q, float* x) {
  H8 u; u.q = q;
  #pragma unroll
  for (int c = 0; c < 8; ++c) x[c] = (float)u.h[c];
}
__device__ __forceinline__ void lse_merge(float& m, float& s, float om, float os) {
  float nm = fmaxf(m, om);
  if (nm == NEGINF) return;
  float acc = 0.f;
  if (s  > 0.f) acc += s  * __expf(m  - nm);
  if (os > 0.f) acc += os * __expf(om - nm);
  m = nm; s = acc;
}
__device__ __forceinline__ float blockReduce256(float v) {
  __shared__ float sh[4];
  #pragma unroll
  for (int off = 32; off >= 1; off >>= 1) v += __shfl_xor(v, off);
  int w = threadIdx.x >> 6;
  if ((threadIdx.x & 63) == 0) sh[w] = v;
  __syncthreads();
  float r = 0.f;
  if (threadIdx.x == 0) r = sh[0] + sh[1] + sh[2] + sh[3];
  __syncthreads();
  return r;
}

__global__ void ContrastiveLoss_83391085019222_kernel(float* out) {
  if (threadIdx.x == 0) { out[0] = 0.5f; out[1] = 0.5f; }
}
__global__ void diag_kernel(float* out, float a, float b) {
  if (threadIdx.x == 0) { out[0] = a; out[1] = b; }
}

/* ---- dtype autodetect: inputs are unit-normalized rows ---- */
__global__ void detect_kernel(const u16* img, float* misc) {
  const int lane = threadIdx.x;  /* 64 */
  float nb = 0.f, nf = 0.f;
  const float* fimg = (const float*)img;
  for (int c = lane * 8; c < lane * 8 + 8; ++c) {
    float xb = bf2f((u32)img[c]);
    nb += xb * xb;
    float xf = fimg[c];
    if (fabsf(xf) < 1e10f) nf += xf * xf; else nf += 1e10f;
  }
  #pragma unroll
  for (int off = 32; off >= 1; off >>= 1) { nb += __shfl_xor(nb, off); nf += __shfl_xor(nf, off); }
  if (lane == 0) {
    float db = fabsf(nb - 1.f);
    float df = fabsf(nf - 1.f);
    if (!(db == db)) db = 1e30f;
    if (!(df == df)) df = 1e30f;
    ((int*)misc)[10] = (df < db) ? 1 : 0;   /* 1 = float32 inputs */
  }
}

/* ---- convert img/txt to bf16 planes ---- */
__global__ void cvt_kernel(const u16* img, const u16* txt,
                           u16* Abf, u16* Bbf, const float* misc) {
  const int isF = ((const int*)misc)[10];
  const int t = blockIdx.x * 256 + threadIdx.x;
  const int base = t * 4;
  if (isF) {
    const float* fi = (const float*)img;
    const float* ft = (const float*)txt;
    ushort4 oa, ob;
    oa.x = f2bf_rne(fi[base+0]); oa.y = f2bf_rne(fi[base+1]);
    oa.z = f2bf_rne(fi[base+2]); oa.w = f2bf_rne(fi[base+3]);
    ob.x = f2bf_rne(ft[base+0]); ob.y = f2bf_rne(ft[base+1]);
    ob.z = f2bf_rne(ft[base+2]); ob.w = f2bf_rne(ft[base+3]);
    *(ushort4*)(Abf + base) = oa;
    *(ushort4*)(Bbf + base) = ob;
  } else {
    *(ushort4*)(Abf + base) = *(const ushort4*)(img + base);
    *(ushort4*)(Bbf + base) = *(const ushort4*)(txt + base);
  }
}

/* init: zero vecs(16400) + errs(256) + rsA0(4096) + csA0(4104) + bar(1024), scale */
__global__ void init_kernel(const u16* ls, float* vecs, float* errs,
                            float* rsA0, float* csA0, int* bar, float* misc) {
  int t = blockIdx.x * 256 + threadIdx.x;
  if (t < 16400) vecs[t] = 0.f;
  if (t < 256)  errs[t] = 0.f;
  if (t < 4096) rsA0[t] = 0.f;
  if (t < 4104) csA0[t] = 0.f;
  if (t < 1024) bar[t] = 0;
  if (t == 0) {
    const int isF = ((const int*)misc)[10];
    float lsv = isF ? ((const float*)ls)[0] : bf2f((u32)ls[0]);
    misc[0] = __expf(lsv);               /* scale = exp(logit_scale) */
  }
}

/* ------- MFMA GEMM (m97 structure): S = Abf x Bbf^T -> fp16 + min ------- */
__global__ __launch_bounds__(256) void gemm_mfma(const u16* Abf, const u16* Bbf,
                                                 u16* S, float* gmin) {
  __shared__ float red[256];
  __shared__ u16 ldsA[128 * 64];
  __shared__ u16 ldsB[128 * 64];
  const int tid = threadIdx.x;
  const int wave = tid >> 6, lane = tid & 63;
  const int wr = wave >> 1, wc = wave & 1;
  const int rb = (int)blockIdx.y * 128;
  const int cb = (int)blockIdx.x * 128;
  const int l15 = lane & 15, q = lane >> 4;
  const int srow = lane >> 3;          /* 0..7 row within 8-row issue group */
  const int scol = (lane & 7) * 8;     /* col element (x8, 16B) */

  frag_cd acc[4][4];
  #pragma unroll
  for (int i = 0; i < 4; ++i)
    #pragma unroll
    for (int j = 0; j < 4; ++j) acc[i][j] = (frag_cd){0.f, 0.f, 0.f, 0.f};

  for (int kt = 0; kt < DD; kt += 64) {
    __syncthreads();                   /* previous compute done before overwrite */
    #pragma unroll
    for (int i = 0; i < 4; ++i) {
      const int R = (wave * 4 + i) * 8;   /* wave-uniform 8-row group */
      gload_lds16(Abf + (size_t)(rb + R + srow) * DD + kt + scol, &ldsA[R * 64]);
      gload_lds16(Bbf + (size_t)(cb + R + srow) * DD + kt + scol, &ldsB[R * 64]);
    }
    __syncthreads();                   /* vmcnt(0) drain: tiles resident */
    #pragma unroll
    for (int s = 0; s < 2; ++s) {
      frag_ab af[4], bfr[4];
      #pragma unroll
      for (int t = 0; t < 4; ++t) {
        af[t]  = *(const frag_ab*)&ldsA[(wr * 64 + t * 16 + l15) * 64 + s * 32 + q * 8];
        bfr[t] = *(const frag_ab*)&ldsB[(wc * 64 + t * 16 + l15) * 64 + s * 32 + q * 8];
      }
      #pragma unroll
      for (int i = 0; i < 4; ++i)
        #pragma unroll
        for (int j = 0; j < 4; ++j)
          acc[i][j] = __builtin_amdgcn_mfma_f32_16x16x32_bf16(af[i], bfr[j], acc[i][j], 0, 0, 0);
    }
  }

  float lmin = 1e30f;
  #pragma unroll
  for (int i = 0; i < 4; ++i) {
    #pragma unroll
    for (int j = 0; j < 4; ++j) {
      #pragma unroll
      for (int r = 0; r < 4; ++r) {
        const int row = rb + wr * 64 + i * 16 + q * 4 + r;
        const int col = cb + wc * 64 + j * 16 + l15;
        u16 h = f2h_hw(acc[i][j][r]);
        lmin = fminf(lmin, h2f_hw(h));
        S[(size_t)row * LDA + col] = h;
      }
    }
  }
  red[tid] = lmin;
  __syncthreads();
  for (int sN = 128; sN >= 1; sN >>= 1) {
    if (tid < sN) red[tid] = fminf(red[tid], red[tid + sN]);
    __syncthreads();
  }
  if (tid == 0) gmin[blockIdx.y * 32 + blockIdx.x] = red[0];
}

/* ------- sims_no -> S col NN + loss_op partial ------- */
__global__ void colvec_kernel(const u16* img, const u16* txt, const u16* tno,
                              u16* S, float* colvals, float* opP, const float* misc) {
  __shared__ float shOp[4];
  const int isF = ((const int*)misc)[10];
  const int wv = threadIdx.x >> 6;
  const int row = (int)(blockIdx.x << 2) + wv;
  const int lane = threadIdx.x & 63;
  const size_t base = (size_t)row * DD + lane * 8;
  float xi[8], xt[8], xn[8];
  if (isF) {
    const float* fi = (const float*)img;
    const float* ft = (const float*)txt;
    const float* fn = (const float*)tno;
    #pragma unroll
    for (int c = 0; c < 8; ++c) { xi[c] = fi[base+c]; xt[c] = ft[base+c]; xn[c] = fn[base+c]; }
  } else {
    Q qi = *(const Q*)(img + base);
    Q qt = *(const Q*)(txt + base);
    Q qn = *(const Q*)(tno + base);
    xi[0]=bflo(qi.x); xi[1]=bfhi(qi.x); xi[2]=bflo(qi.y); xi[3]=bfhi(qi.y);
    xi[4]=bflo(qi.z); xi[5]=bfhi(qi.z); xi[6]=bflo(qi.w); xi[7]=bfhi(qi.w);
    xt[0]=bflo(qt.x); xt[1]=bfhi(qt.x); xt[2]=bflo(qt.y); xt[3]=bfhi(qt.y);
    xt[4]=bflo(qt.z); xt[5]=bfhi(qt.z); xt[6]=bflo(qt.w); xt[7]=bfhi(qt.w);
    xn[0]=bflo(qn.x); xn[1]=bfhi(qn.x); xn[2]=bflo(qn.y); xn[3]=bfhi(qn.y);
    xn[4]=bflo(qn.z); xn[5]=bfhi(qn.z); xn[6]=bflo(qn.w); xn[7]=bfhi(qn.w);
  }
  float sn = 0.f, cs = 0.f;
  #pragma unroll
  for (int c = 0; c < 8; ++c) { sn += xi[c]*xn[c]; cs += xt[c]*xn[c]; }
  #pragma unroll
  for (int off = 32; off >= 1; off >>= 1) { sn += __shfl_xor(sn, off); cs += __shfl_xor(cs, off); }
  if (lane == 0) {
    colvals[row] = sn;
    S[(size_t)row * LDA + NN] = f2h_hw(sn);
    shOp[wv] = fmaxf(cs + 0.2f, 0.f) + fmaxf(-0.7f - cs, 0.f);
  }
  __syncthreads();
  if (threadIdx.x == 0) opP[blockIdx.x] = shOp[0] + shOp[1] + shOp[2] + shOp[3];
}

__global__ void reduce_kernel(const float* gmin, const float* colvals,
                              const float* opP, float* misc) {
  __shared__ float smin[256];
  __shared__ float ssum[256];
  float mn = 1e30f, sm = 0.f;
  for (int i = threadIdx.x; i < 1024; i += 256) mn = fminf(mn, gmin[i]);
  for (int i = threadIdx.x; i < 4096; i += 256) mn = fminf(mn, h2f_hw(f2h_hw(colvals[i])));
  for (int i = threadIdx.x; i < 1024; i += 256) sm += opP[i];
  smin[threadIdx.x] = mn; ssum[threadIdx.x] = sm;
  __syncthreads();
  for (int sN = 128; sN >= 1; sN >>= 1) {
    if (threadIdx.x < sN) {
      smin[threadIdx.x] = fminf(smin[threadIdx.x], smin[threadIdx.x + sN]);
      ssum[threadIdx.x] += ssum[threadIdx.x + sN];
    }
    __syncthreads();
  }
  if (threadIdx.x == 0) {
    float maxC = 1.0f - smin[0];         /* max(1-S) = 1 - min(S) */
    float a = 1.0f / (maxC * REGc);
    misc[1] = a;
    misc[4] = ssum[0];
    misc[5] = __expf(-a);                /* ea */
    misc[6] = a * 1.4426950408889634f;   /* b = a*log2(e) for exp2 fast path */
  }
}

__global__ void preds_kernel(const u16* S, const float* misc, float* preds) {
  const int row = (int)(blockIdx.x << 2) + (int)(threadIdx.x >> 6);
  const int lane = threadIdx.x & 63;
  const float scale = misc[0];
  const u16* Sr = S + (size_t)row * LDA;
  float m = NEGINF, s = 0.f;
  for (int it = 0; it < 8; ++it) {
    const int j0 = (it << 9) + (lane << 3);
    float x[8];
    unpack8(*(const Q*)(Sr + j0), x);
    float lm = NEGINF;
    #pragma unroll
    for (int c = 0; c < 8; ++c) { x[c] *= scale; lm = fmaxf(lm, x[c]); }
    float lsum = 0.f;
    #pragma unroll
    for (int c = 0; c < 8; ++c) lsum += __expf(x[c] - lm);
    lse_merge(m, s, lm, lsum);
  }
  #pragma unroll
  for (int off = 32; off >= 1; off >>= 1) {
    float om = __shfl_xor(m, off), os = __shfl_xor(s, off);
    lse_merge(m, s, om, os);
  }
  if (lane == 0) {
    float sii = h2f_hw(Sr[row]);
    preds[row] = __expf(scale * sii - m) / s;
  }
}

/* ------- nc rank: one block per row ------- */
__global__ void rank_kernel(const float* preds, int* is_nc) {
  const int i = blockIdx.x;
  const float pv = preds[i];
  float cnt = 0.f;
  for (int k2 = threadIdx.x; k2 < NN; k2 += 256) {
    float pk = preds[k2];
    cnt += (pk < pv || (pk == pv && k2 < i)) ? 1.f : 0.f;
  }
  cnt = blockReduce256(cnt);
  if (threadIdx.x == 0) is_nc[i] = (cnt < (float)NCNUM) ? 1 : 0;
}

__device__ __forceinline__ bool unmasked(int j, int r, bool ncr) {
  return (j == NN) ? ncr : !((j == r) && ncr);
}

/* ------- fence-free monotonic tree barrier (round-24 proven design) ------- */
__device__ __forceinline__ void gridbar(int* bar, int bid, int phase, bool& dead) {
  __syncthreads();
  if (threadIdx.x == 0 && !dead) {
    const int g = bid & 31;
    if (__hip_atomic_fetch_add(&bar[g << 4], 1, __ATOMIC_RELAXED,
                               __HIP_MEMORY_SCOPE_AGENT) == 32 * phase - 1) {
      if (__hip_atomic_fetch_add(&bar[32 << 4], 1, __ATOMIC_RELAXED,
                                 __HIP_MEMORY_SCOPE_AGENT) == 32 * phase - 1) {
        #pragma unroll
        for (int gg = 0; gg < 32; ++gg)
          __hip_atomic_store(&bar[(gg << 4) + 8], phase, __ATOMIC_RELAXED,
                             __HIP_MEMORY_SCOPE_AGENT);
      }
    }
    int spins = 0;
    while (__hip_atomic_load(&bar[(g << 4) + 8], __ATOMIC_RELAXED,
                             __HIP_MEMORY_SCOPE_AGENT) < phase) {
      __builtin_amdgcn_s_sleep(2);
      if (++spins > (1 << 21)) { dead = true; break; }   /* ~0.1s sticky cap */
    }
  }
  __syncthreads();
}

/* ------- one sinkhorn sub-step with cached E; prev sums preloaded ---- */
template<int RB, int FIN>
__device__ __forceinline__ void substep(
    float (&Ec)[8][8], int k,
    int c1, int c2, int c1p, int c2p,
    float pr, float prN,
    float* outRow, float* outCol,
    float* z1, float* z2, int nz1, int nz2,
    float* errs1, float* errs2,
    float* uvec, float* utvec, float* vvec, float* vtvec,
    float* shW1, float* shW2, float (*shAcc)[128], float* sh4096,
    float* se,
    float ea, int rt, int ct, int bid, int tid, int tc, int tr,
    int j0c, int r0, int cbase, bool isLast) {

  const int gRow = RB ? c2 : c1;
  const int gCol = RB ? c1 : c2;

  if (!FIN) {
    const int z = bid * 256 + tid;          /* 8200 < 262144: one shot */
    if (z < nz1) stu(&z1[z], 0.f);
    else if (z - nz1 < nz2) stu(&z2[z - nz1], 0.f);
  }

  float errd = 0.f;
  if (tid < 128) {
    const int i = r0 + tid;
    float w = 0.f;
    if (!RB) {
      if (!FIN && !gCol) w = (k == 0) ? ea : ea / (4096.0f * pr);
      if (ct == 0 && k >= 1 && !c2p) stu(&vtvec[i], REGc * (-LOGN - __logf(pr)));
    } else {
      if (!gCol) {
        w = ea / (4096.0f * pr);
        if (ct == 0) {
          float un = REGc * (-LOGN - __logf(pr));
          errd = fabsf(un - uvec[i]);
          uvec[i] = un;
        }
      }
    }
    shW2[tid] = w;
  } else {
    const int j = cbase + (tid - 128);
    float w = 0.f;
    if (!RB) {
      if (!FIN && !gRow) w = (k == 0) ? ea : ea / (4097.0f * pr);
      if (rt == 0 && k >= 1 && !c1p) stu(&vvec[j], REGc * (-LOGM - __logf(pr)));
    } else {
      if (!gRow) {
        w = ea / (4097.0f * pr);
        if (rt == 0) {
          float un = REGc * (-LOGM - __logf(pr));
          errd = fabsf(un - utvec[j]);
          utvec[j] = un;
        }
      }
    }
    shW1[tid - 128] = w;
    if (isLast && tid == 128) {        /* col 4096 sidecar weight */
      float w2 = 0.f;
      if (!RB) {
        if (!FIN && !gRow) w2 = (k == 0) ? ea : ea / (4097.0f * prN);
        if (rt == 0 && k >= 1 && !c1p) stu(&vvec[NN], REGc * (-LOGM - __logf(prN)));
      } else {
        if (!gRow) {
          w2 = ea / (4097.0f * prN);
          if (rt == 0) {
            float un = REGc * (-LOGM - __logf(prN));
            errd += fabsf(un - utvec[NN]);
            utvec[NN] = un;
          }
        }
      }
      shW1[128] = w2;
    }
  }
  __syncthreads();

  if (!FIN && !(gRow && gCol)) {
    float W1l[8];
    #pragma unroll
    for (int c = 0; c < 8; ++c) W1l[c] = shW1[j0c + c];
    float cs[8];
    #pragma unroll
    for (int c = 0; c < 8; ++c) cs[c] = 0.f;
    const float w4096 = isLast ? shW1[128] : 0.f;
    #pragma unroll
    for (int st = 0; st < 8; ++st) {
      const int rr = (st << 4) + tr;
      if (!gCol) {
        const float Wr = shW2[rr];
        #pragma unroll
        for (int c = 0; c < 8; ++c) cs[c] = fmaf(Ec[st][c], Wr, cs[c]);
      }
      if (!gRow) {
        float rs = 0.f;
        #pragma unroll
        for (int c = 0; c < 8; ++c) rs = fmaf(Ec[st][c], W1l[c], rs);
        #pragma unroll
        for (int off = 8; off >= 1; off >>= 1) rs += __shfl_xor(rs, off);
        if (tc == 0) {
          if (isLast) rs += sh4096[rr] * w4096;
          atomicAdd(&outRow[r0 + rr], rs);
        }
      }
    }
    if (!gCol) {
      #pragma unroll
      for (int c = 0; c < 8; ++c) shAcc[tr][j0c + c] = cs[c];
      __syncthreads();
      if (tid < 128) {
        float s2 = 0.f;
        #pragma unroll
        for (int g = 0; g < 16; ++g) s2 += shAcc[g][tid];
        atomicAdd(&outCol[cbase + tid], s2);
      }
      if (isLast && tid >= 128 && tid < 192) {   /* colsum for j=4096 */
        const int l = tid - 128;
        float s3 = sh4096[l] * shW2[l] + sh4096[l + 64] * shW2[l + 64];
        #pragma unroll
        for (int off = 32; off >= 1; off >>= 1) s3 += __shfl_xor(s3, off);
        if (l == 0) atomicAdd(&outCol[NN], s3);
      }
    }
  }

  if (RB) {
    float e2 = errd;
    #pragma unroll
    for (int off = 32; off >= 1; off >>= 1) e2 += __shfl_xor(e2, off);
    if ((tid & 63) == 0) se[tid >> 6] = e2;
    __syncthreads();
    if (tid == 0) {
      if (ct == 0) atomicAdd(&errs1[k], se[0] + se[1]);
      if (rt == 0) atomicAdd(&errs2[k], se[2] + se[3]);
    }
  }
}

/* ------- persistent sinkhorn + fused final/combine/loss/finish ------- */
__global__ __launch_bounds__(256, 4) void sink_persist(
    const u16* S, const float* misc, float* errs1, float* errs2,
    float* uvec, float* utvec, float* vvec, float* vtvec,
    float* rsA0, float* rsA1, float* csA0, float* csA1,
    float* rsB0, float* rsB1, float* csB0, float* csB1,
    const int* is_nc, int* bar,
    float* rowLm, float* rowLs, float* rowGs,
    float* colLm, float* colLs, float* colGs,
    float* LSMrow, float* LBLm, float* LBLs,
    float* LSMcol, float* LBTm, float* LBTs,
    float* imgP, float* txtP, float* out) {
  __shared__ float shW1[129];
  __shared__ float shW2[128];
  __shared__ float shAcc[16][128];
  __shared__ float sh4096[128];
  __shared__ int   shG[4];
  __shared__ float se[4];
  __shared__ float shm[16][128];
  __shared__ float shs[16][128];

  const int tid = threadIdx.x;
  const int rt = blockIdx.x, ct = blockIdx.y;
  const int bid = ct * 32 + rt;
  const int cbase = ct << 7, r0 = rt << 7;
  const float a = misc[1], ea = misc[5], b = misc[6];
  const int tc = tid & 15, tr = tid >> 4;
  const int j0c = tc << 3;
  const bool isLast = (ct == 31);

  /* ---- build E tile in registers, masks baked in ---- */
  float Ec[8][8];
  if (rt != ct) {
    #pragma unroll
    for (int st = 0; st < 8; ++st) {
      const int rr = (st << 4) + tr;
      H8 hh; hh.q = *(const Q*)(S + (size_t)(r0 + rr) * LDA + cbase + j0c);
      #pragma unroll
      for (int c = 0; c < 8; ++c) Ec[st][c] = exp2_fast((float)hh.h[c] * b);
    }
  } else {
    #pragma unroll
    for (int st = 0; st < 8; ++st) {
      const int rr = (st << 4) + tr;
      const int r = r0 + rr;
      float xv[8];
      unpack8(*(const Q*)(S + (size_t)r * LDA + cbase + j0c), xv);
      const bool ncr = (is_nc[r] != 0);
      #pragma unroll
      for (int c = 0; c < 8; ++c) {
        float e = __expf(xv[c] * a);
        if ((j0c + c == rr) && ncr) e = 0.f;   /* diag mask (cbase==r0) */
        Ec[st][c] = e;
      }
    }
  }
  if (isLast && tid < 128) {
    const int r = r0 + tid;
    float x = h2f_hw(S[(size_t)r * LDA + NN]);
    sh4096[tid] = (is_nc[r] != 0) ? __expf(x * a) : 0.f;
  }
  __syncthreads();

  bool dead = false;
  int phase = 0;
  for (int k = 0; k < 100; ++k) {
    const int p = k & 1;
    const int q2 = 1 - p;
    const int pm = (k > 0) ? q2 : 0;
    /* prev loads for substep A + gate loads: issued CONCURRENTLY */
    const float* pRowA = pm ? rsB1 : rsB0;
    const float* pColA = pm ? csB1 : csB0;
    float prA = 0.f, prAN = 0.f;
    if (tid < 128) {
      prA = ldu(&pRowA[r0 + tid]);
    } else {
      prA = ldu(&pColA[cbase + (tid - 128)]);
      if (isLast && tid == 128) prAN = ldu(&pColA[NN]);
    }
    if (tid < 4) {
      const int kk = k - 1 - (tid >> 1);
      const float* ep = (tid & 1) ? errs2 : errs1;
      shG[tid] = (kk >= 0) && (ldu(&ep[kk]) < THRESHc);
    }
    __syncthreads();
    const int c1 = shG[0], c2 = shG[1], c1p = shG[2], c2p = shG[3];
    if (c1 && c2 && c1p && c2p) break;   /* remaining substeps provably no-op */

    substep<0, 0>(Ec, k, c1, c2, c1p, c2p, prA, prAN,
        p ? rsA1 : rsA0, p ? csA1 : csA0,
        p ? csB1 : csB0, p ? rsB1 : rsB0, 4104, 4096,
        errs1, errs2, uvec, utvec, vvec, vtvec,
        shW1, shW2, shAcc, sh4096, se,
        ea, rt, ct, bid, tid, tc, tr, j0c, r0, cbase, isLast);
    gridbar(bar, bid, ++phase, dead);

    const float* pRowB = p ? rsA1 : rsA0;
    const float* pColB = p ? csA1 : csA0;
    float prB = 0.f, prBN = 0.f;
    if (tid < 128) {
      prB = ldu(&pRowB[r0 + tid]);
    } else {
      prB = ldu(&pColB[cbase + (tid - 128)]);
      if (isLast && tid == 128) prBN = ldu(&pColB[NN]);
    }
    substep<1, 0>(Ec, k, c1, c2, c1p, c2p, prB, prBN,
        p ? rsB1 : rsB0, p ? csB1 : csB0,
        q2 ? rsA1 : rsA0, q2 ? csA1 : csA0, 4096, 4104,
        errs1, errs2, uvec, utvec, vvec, vtvec,
        shW1, shW2, shAcc, sh4096, se,
        ea, rt, ct, bid, tid, tc, tr, j0c, r0, cbase, isLast);
    gridbar(bar, bid, ++phase, dead);
  }

  /* final weight-only step (k=100); gates for k=100 (all-true if broken) */
  {
    float prF = 0.f, prFN = 0.f;
    if (tid < 128) {
      prF = ldu(&rsB1[r0 + tid]);
    } else {
      prF = ldu(&csB1[cbase + (tid - 128)]);
      if (isLast && tid == 128) prFN = ldu(&csB1[NN]);
    }
    if (tid < 4) {
      const int kk = 99 - (tid >> 1);
      const float* ep = (tid & 1) ? errs2 : errs1;
      shG[tid] = (ldu(&ep[kk]) < THRESHc);
    }
    __syncthreads();
    substep<0, 1>(Ec, 100, shG[0], shG[1], shG[2], shG[3], prF, prFN,
        rsA0, csA0, rsA0, csA0, 0, 0,
        errs1, errs2, uvec, utvec, vvec, vtvec,
        shW1, shW2, shAcc, sh4096, se,
        ea, rt, ct, bid, tid, tc, tr, j0c, r0, cbase, isLast);
  }

  /* ======== fused tail ======== */
  gridbar(bar, bid, ++phase, dead);
  const float scale = misc[0];

  /* ---- stage F: final_pass for tile (rt, ct); all j < NN here ----
     per-block vectors staged into LDS once via coalesced plain loads
     (fresh: stu-written before the gridbar, never plain-touched before) */
  {
    if (tid < 128) shAcc[0][tid] = vvec[cbase + tid] * INVREG;
    else           shAcc[1][tid - 128] = vtvec[r0 + (tid - 128)] * INVREG;
    __syncthreads();
    float wc[8];
    #pragma unroll
    for (int c = 0; c < 8; ++c) wc[c] = shAcc[0][j0c + c];
    float cLm[8], cLs[8], cGs[8];
    #pragma unroll
    for (int c = 0; c < 8; ++c) { cLm[c] = NEGINF; cLs[c] = 0.f; cGs[c] = 0.f; }
    for (int st = 0; st < 8; ++st) {
      const int r = r0 + (st << 4) + tr;
      float xv[8], lg[8]; unsigned um = 0;
      float raw[8];
      unpack8(*(const Q*)(S + (size_t)r * LDA + cbase + j0c), raw);
      const bool ncr = (is_nc[r] != 0);
      const float vtr = shAcc[1][(st << 4) + tr];
      #pragma unroll
      for (int c = 0; c < 8; ++c) {
        xv[c] = raw[c] * a;
        lg[c] = scale * raw[c];
        cGs[c] += __expf(lg[c]);
        if (!((cbase + j0c + c == r) && ncr)) {
          um |= 1u << c;
          float e2 = xv[c] + vtr;
          float nm = fmaxf(cLm[c], e2);
          cLs[c] = cLs[c] * __expf(cLm[c] - nm) + __expf(e2 - nm);
          cLm[c] = nm;
        }
      }
      float rsG = 0.f;
      #pragma unroll
      for (int c = 0; c < 8; ++c) rsG += __expf(lg[c]);
      #pragma unroll
      for (int off = 8; off >= 1; off >>= 1) rsG += __shfl_xor(rsG, off);
      float rmL = NEGINF;
      #pragma unroll
      for (int c = 0; c < 8; ++c) if (um >> c & 1u) rmL = fmaxf(rmL, xv[c] + wc[c]);
      #pragma unroll
      for (int off = 8; off >= 1; off >>= 1) rmL = fmaxf(rmL, __shfl_xor(rmL, off));
      float rsL = 0.f;
      if (rmL > NEGINF) {
        #pragma unroll
        for (int c = 0; c < 8; ++c) if (um >> c & 1u) rsL += __expf(xv[c] + wc[c] - rmL);
      }
      #pragma unroll
      for (int off = 8; off >= 1; off >>= 1) rsL += __shfl_xor(rsL, off);
      if (tc == 0) {
        stu(&rowGs[ct * NN + r], rsG);
        stu(&rowLm[ct * NN + r], rmL);
        stu(&rowLs[ct * NN + r], rsL);
      }
    }
    #pragma unroll
    for (int c = 0; c < 8; ++c) { shm[tr][j0c + c] = cLm[c]; shs[tr][j0c + c] = cLs[c]; }
    __syncthreads();
    if (tid < 128) {
      float m = NEGINF, s = 0.f;
      #pragma unroll
      for (int g = 0; g < 16; ++g) lse_merge(m, s, shm[g][tid], shs[g][tid]);
      stu(&colLm[rt * LDA + cbase + tid], m);
      stu(&colLs[rt * LDA + cbase + tid], s);
    }
    __syncthreads();
    #pragma unroll
    for (int c = 0; c < 8; ++c) shs[tr][j0c + c] = cGs[c];
    __syncthreads();
    if (tid < 128) {
      float s = 0.f;
      #pragma unroll
      for (int g = 0; g < 16; ++g) s += shs[g][tid];
      stu(&colGs[rt * LDA + cbase + tid], s);
    }
    /* sidecar: pseudo-tile ct=32 (the j==4096 column) */
    if (isLast) {
      __syncthreads();
      const float wcN = vvec[NN] * INVREG;
      if (tid < 128) {
        const int r = r0 + tid;
        float rawN = h2f_hw(S[(size_t)r * LDA + NN]);
        int ncrN = is_nc[r];
        float rsG = __expf(scale * rawN);
        float xvN = rawN * a;
        float rmL = ncrN ? (xvN + wcN) : NEGINF;
        float rsL = ncrN ? 1.f : 0.f;      /* exp(0) == 1 exact */
        stu(&rowGs[32 * NN + r], rsG);
        stu(&rowLm[32 * NN + r], rmL);
        stu(&rowLs[32 * NN + r], rsL);
      }
      float cLmN = NEGINF, cLsN = 0.f, cGsN = 0.f;
      if (tc == 0) {
        #pragma unroll
        for (int st = 0; st < 8; ++st) {
          const int r = r0 + (st << 4) + tr;
          float rw = h2f_hw(S[(size_t)r * LDA + NN]);
          float xvN = rw * a;
          cGsN += __expf(scale * rw);
          if (is_nc[r]) {
            float vtr = shAcc[1][(st << 4) + tr];
            float e2 = xvN + vtr;
            float nm = fmaxf(cLmN, e2);
            cLsN = cLsN * __expf(cLmN - nm) + __expf(e2 - nm);
            cLmN = nm;
          }
        }
      }
      __syncthreads();
      if (tc == 0) { shm[tr][0] = cLmN; shs[tr][0] = cLsN; shAcc[2][tr] = cGsN; }
      __syncthreads();
      if (tid == 0) {
        float m = NEGINF, s = 0.f, sg = 0.f;
        for (int g = 0; g < 16; ++g) {
          lse_merge(m, s, shm[g][0], shs[g][0]);
          sg += shAcc[2][g];
        }
        stu(&colLm[rt * LDA + NN], m);
        stu(&colLs[rt * LDA + NN], s);
        stu(&colGs[rt * LDA + NN], sg);
      }
    }
  }
  gridbar(bar, bid, ++phase, dead);

  /* ---- stage C: combine, 8193 outputs, 1 thread each, serial order;
         plain loads (stu-written before gridbar, first plain touch) ---- */
  {
    int o = bid * 8 + tid;
    bool act = (tid < 8);
    if (bid == 1023 && tid == 8) { act = true; o = 8192; }
    if (act) {
      if (o < 4096) {
        const int i = o;
        float m = NEGINF, s = 0.f, sg = 0.f;
        for (int t = 0; t < 33; ++t) {
          lse_merge(m, s, rowLm[t * NN + i], rowLs[t * NN + i]);
          sg += rowGs[t * NN + i];
        }
        stu(&LBLm[i], m); stu(&LBLs[i], s);
        stu(&LSMrow[i], __logf(sg));
      } else {
        const int j = o - 4096;
        float m = NEGINF, s = 0.f, sg = 0.f;
        for (int t = 0; t < 32; ++t) {
          lse_merge(m, s, colLm[t * LDA + j], colLs[t * LDA + j]);
          sg += colGs[t * LDA + j];
        }
        stu(&LBTm[j], m); stu(&LBTs[j], s);
        stu(&LSMcol[j], __logf(sg));
      }
    }
  }
  gridbar(bar, bid, ++phase, dead);

  /* ---- stage L: loss_pass for tile (rt, ct) + sidecar;
         8 per-block vectors staged into LDS via plain loads ---- */
  {
    if (tid < 128) {
      const int j = cbase + tid;
      shm[0][tid] = vvec[j] * INVREG;
      shm[1][tid] = LBTm[j];
      shm[2][tid] = 1.f / LBTs[j];
      shm[3][tid] = LSMcol[j];
    } else {
      const int r = r0 + (tid - 128);
      shm[4][tid - 128] = vtvec[r] * INVREG;
      shm[5][tid - 128] = LBLm[r];
      shm[6][tid - 128] = 1.f / LBLs[r];
      shm[7][tid - 128] = LSMrow[r];
    }
    __syncthreads();
    float vcw[8], bm[8], bsi[8], cg[8];
    #pragma unroll
    for (int c = 0; c < 8; ++c) {
      vcw[c] = shm[0][j0c + c];
      bm[c]  = shm[1][j0c + c];
      bsi[c] = shm[2][j0c + c];
      cg[c]  = shm[3][j0c + c];
    }
    float sImg = 0.f, sTxt = 0.f;
    for (int st = 0; st < 8; ++st) {
      const int rr = (st << 4) + tr;
      const int r = r0 + rr;
      float raw[8];
      unpack8(*(const Q*)(S + (size_t)r * LDA + cbase + j0c), raw);
      const bool ncr = (is_nc[r] != 0);
      const float vtr = shm[4][rr];
      const float rm = shm[5][rr], rsi = shm[6][rr], rg = shm[7][rr];
      #pragma unroll
      for (int c = 0; c < 8; ++c) {
        const int j = cbase + j0c + c;
        float xv = raw[c] * a;
        float lgt = scale * raw[c];
        bool unm = !((j == r) && ncr);
        bool lv = (j == r) && !ncr;
        float rr2 = unm ? __expf(xv + vcw[c] - rm) * rsi : 0.f;
        float t = GAM * rr2 + (lv ? 0.2f : 0.f);
        if (t > 0.f) sImg += t * (__logf(t) - (lgt - rg));
        float r2 = unm ? __expf(xv + vtr - bm[c]) * bsi[c] : 0.f;
        float t2 = GAM * r2 + (lv ? 0.2f : 0.f);
        if (t2 > 0.f) sTxt += t2 * (__logf(t2) - (lgt - cg[c]));
      }
    }
    sImg = blockReduce256(sImg);
    sTxt = blockReduce256(sTxt);
    if (tid == 0) {
      stu(&imgP[rt * 33 + ct], sImg);
      stu(&txtP[rt * 33 + ct], sTxt);
    }
    if (isLast) {
      float sI = 0.f, sT = 0.f;
      if (tc == 0) {
        const float vcwN = vvec[NN] * INVREG;
        const float bmN = LBTm[NN];
        const float bsiN = 1.f / LBTs[NN];
        const float cgN = LSMcol[NN];
        #pragma unroll
        for (int st = 0; st < 8; ++st) {
          const int rr = (st << 4) + tr;
          const int r = r0 + rr;
          float rw = h2f_hw(S[(size_t)r * LDA + NN]);
          const bool ncr = (is_nc[r] != 0);
          float xv = rw * a;
          float lgt = scale * rw;
          const float vtr = shm[4][rr];
          const float rm = shm[5][rr], rsi = shm[6][rr], rg = shm[7][rr];
          float rr2 = ncr ? __expf(xv + vcwN - rm) * rsi : 0.f;
          float t = GAM * rr2 + (ncr ? 0.2f : 0.f);
          if (t > 0.f) sI += t * (__logf(t) - (lgt - rg));
          float r2 = ncr ? __expf(xv + vtr - bmN) * bsiN : 0.f;
          float t2 = GAM * r2 + (ncr ? 0.2f : 0.f);
          if (t2 > 0.f) sT += t2 * (__logf(t2) - (lgt - cgN));
        }
      }
      sI = blockReduce256(sI);
      sT = blockReduce256(sT);
      if (tid == 0) {
        stu(&imgP[rt * 33 + 32], sI);
        stu(&txtP[rt * 33 + 32], sT);
      }
    }
  }
  gridbar(bar, bid, ++phase, dead);

  /* ---- stage E: finish (block 0, serial order identical to standalone;
         plain loads) */
  if (bid == 0) {
    float vi = 0.f, vtx = 0.f;
    for (int idx = tid; idx < 1056; idx += 256) {
      vi += imgP[idx];
      vtx += txtP[idx];
    }
    vi = blockReduce256(vi);
    vtx = blockReduce256(vtx);
    if (tid == 0) {
      float loss_img = vi / 4096.0f;
      float loss_txt = vtx / 4097.0f;
      float loss_ul = 0.5f * (loss_img + loss_txt);
      float loss_op = misc[4] / 4096.0f;
      if (vi == 0.f && vtx == 0.f) loss_ul = 777.0f;
      if (!(loss_ul == loss_ul))   loss_ul = 888.0f;
      out[0] = loss_ul;
      out[1] = loss_op;
    }
  }
}

extern "C" void kernel_launch(void* const* d_in, const int* in_sizes, int n_in,
                              void* d_out, int out_size, void* d_ws, size_t ws_size,
                              hipStream_t stream) {
  (void)in_sizes; (void)n_in; (void)out_size;
  const u16* img = (const u16*)d_in[0];
  const u16* txt = (const u16*)d_in[1];
  const u16* tno = (const u16*)d_in[2];
  const u16* ls  = (const u16*)d_in[3];
  float* out = (float*)d_out;

  ContrastiveLoss_83391085019222_kernel<<<1, 64, 0, stream>>>(out);

  size_t off = 0;
  char* w = (char*)d_ws;
  u16* S; u16* Abf; u16* Bbf;
  float *rsA0, *rsA1, *csA0, *csA1, *rsB0, *rsB1, *csB0, *csB1, *errs;
  float *rowLm, *rowLs, *rowGs, *colLm, *colLs, *colGs;
  float *vecs, *preds, *colvals, *gmin, *opP;
  float *LSMrow, *LBLm, *LBLs, *LSMcol, *LBTm, *LBTs, *imgP, *txtP, *misc;
  int* is_nc; int* bar;
  #define ALLOC(ptr, type, nbytes) ptr = (type)(w + off); off = (off + (size_t)(nbytes) + 255) & ~(size_t)255
  ALLOC(S,      u16*,   (size_t)NN * LDA * 2);
  ALLOC(Abf,    u16*,   (size_t)NN * DD * 2);
  ALLOC(Bbf,    u16*,   (size_t)NN * DD * 2);
  ALLOC(rsA0,   float*, 4096 * 4);
  ALLOC(rsA1,   float*, 4096 * 4);
  ALLOC(csA0,   float*, 4104 * 4);
  ALLOC(csA1,   float*, 4104 * 4);
  ALLOC(rsB0,   float*, 4096 * 4);
  ALLOC(rsB1,   float*, 4096 * 4);
  ALLOC(csB0,   float*, 4104 * 4);
  ALLOC(csB1,   float*, 4104 * 4);
  ALLOC(errs,   float*, 256 * 4);
  ALLOC(rowLm,  float*, (size_t)33 * NN * 4);
  ALLOC(rowLs,  float*, (size_t)33 * NN * 4);
  ALLOC(rowGs,  float*, (size_t)33 * NN * 4);
  ALLOC(colLm,  float*, (size_t)32 * LDA * 4);
  ALLOC(colLs,  float*, (size_t)32 * LDA * 4);
  ALLOC(colGs,  float*, (size_t)32 * LDA * 4);
  ALLOC(vecs,   float*, 16400 * 4);
  ALLOC(preds,  float*, NN * 4);
  ALLOC(is_nc,  int*,   NN * 4);
  ALLOC(colvals,float*, NN * 4);
  ALLOC(gmin,   float*, 1024 * 4);
  ALLOC(opP,    float*, 1024 * 4);
  ALLOC(LSMrow, float*, NN * 4);
  ALLOC(LBLm,   float*, NN * 4);
  ALLOC(LBLs,   float*, NN * 4);
  ALLOC(LSMcol, float*, LDA * 4);
  ALLOC(LBTm,   float*, LDA * 4);
  ALLOC(LBTs,   float*, LDA * 4);
  ALLOC(imgP,   float*, 1056 * 4);
  ALLOC(txtP,   float*, 1056 * 4);
  ALLOC(bar,    int*,   4096);
  ALLOC(misc,   float*, 64);
  #undef ALLOC

  if (ws_size < off) {
    diag_kernel<<<1, 64, 0, stream>>>(out, -(float)(ws_size / 1000000.0),
                                      -(float)(off / 1000000.0));
    return;
  }

  float* uvec  = vecs;
  float* vvec  = vecs + 4096;
  float* utvec = vecs + 8200;
  float* vtvec = vecs + 12304;
  float* errs1 = errs;
  float* errs2 = errs + 128;

  detect_kernel<<<1, 64, 0, stream>>>(img, misc);
  cvt_kernel<<<2048, 256, 0, stream>>>(img, txt, Abf, Bbf, misc);
  init_kernel<<<65, 256, 0, stream>>>(ls, vecs, errs, rsA0, csA0, bar, misc);
  gemm_mfma<<<dim3(32, 32), 256, 0, stream>>>(Abf, Bbf, S, gmin);
  colvec_kernel<<<1024, 256, 0, stream>>>(img, txt, tno, S, colvals, opP, misc);
  reduce_kernel<<<1, 256, 0, stream>>>(gmin, colvals, opP, misc);

  preds_kernel<<<1024, 256, 0, stream>>>(S, misc, preds);
  rank_kernel<<<4096, 256, 0, stream>>>(preds, is_nc);

  /* persistent sinkhorn + fused tail: 1024 blocks, 4/CU by launch bounds */
  sink_persist<<<dim3(32, 32), 256, 0, stream>>>(S, misc, errs1, errs2,
      uvec, utvec, vvec, vtvec,
      rsA0, rsA1, csA0, csA1, rsB0, rsB1, csB0, csB1,
      is_nc, bar,
      rowLm, rowLs, rowGs, colLm, colLs, colGs,
      LSMrow, LBLm, LBLs, LSMcol, LBTm, LBTs,
      imgP, txtP, out);
}